// Round 5
// baseline (775.761 us; speedup 1.0000x reference)
//
#include <hip/hip_runtime.h>
#include <hip/hip_bf16.h>
#include <math.h>

typedef unsigned short u16;
typedef u16 u16x4 __attribute__((ext_vector_type(4)));
typedef u16 u16x8 __attribute__((ext_vector_type(8)));
typedef short s16x8 __attribute__((ext_vector_type(8)));
typedef float f32x4 __attribute__((ext_vector_type(4)));

#define DEVI static __device__ __forceinline__

DEVI float bf2f(u16 u){ unsigned v=((unsigned)u)<<16; float f; __builtin_memcpy(&f,&v,4); return f; }
DEVI u16 f2bf(float f){ unsigned u; __builtin_memcpy(&u,&f,4); u=(u+0x7FFFu+((u>>16)&1u))>>16; return (u16)u; }

// async global->LDS, 16B per lane. LDS dest must be wave-uniform base (lane scatter
// comes from the per-lane GLOBAL address -> fragment-order pre-permutation).
DEVI void gload16(const u16* g, u16* l){
  __builtin_amdgcn_global_load_lds(
      (const __attribute__((address_space(1))) void*)(unsigned long long)g,
      (__attribute__((address_space(3))) void*)(unsigned int)(unsigned long long)l,
      16, 0, 0);
}

// ---------------- workspace layout (bytes) ----------------
constexpr size_t AL(size_t x){ return (x+511)&~(size_t)511; }
constexpr size_t sACT =8ull*1600*256*2;                       // one NHWC bf16 activation (6.55 MB)
constexpr size_t oXPAD=0;                constexpr size_t sXPAD=8ull*46*46*256*2; // stem padded input; reused as xm
constexpr size_t oT1P =AL(oXPAD+sXPAD);  constexpr size_t sT1P=8ull*42*42*64*2;   // cb1 out, padded
constexpr size_t oSTAT=AL(oT1P+sT1P);    constexpr size_t sSTAT=512;              // gn1[16]+gn2[16] floats
constexpr size_t ZERO_BYTES=oSTAT+sSTAT;
constexpr size_t oWST =AL(ZERO_BYTES);   constexpr size_t sWST=6553600;           // stem w bf16 [49][256][256]; reused as xmgn
constexpr size_t oWCB2=AL(oWST+sWST);    constexpr size_t sWCB2=9*64*64*2;
constexpr size_t oWSM =AL(oWCB2+sWCB2);  constexpr size_t sWSM=901120ull*2;       // all 1x1 weights bf16
constexpr size_t oC2  =AL(oWSM+sWSM);    constexpr size_t sC2=1024;
constexpr size_t oSTEM=AL(oC2+sC2);                                                // stem conv out
constexpr size_t oX1  =AL(oSTEM+sACT);
constexpr size_t oT2  =AL(oX1+sACT);     constexpr size_t sT2=8ull*1600*64*2;
constexpr size_t oRRES=AL(oT2+sT2);                                                // cbres out; reused as hdw + conv partials
constexpr size_t oXC  =AL(oRRES+sACT);
constexpr size_t oZ   =AL(oXC+sACT);
constexpr size_t oZT  =AL(oZ+sACT);                                                // z transposed NCHW
constexpr size_t oX2  =AL(oZT+sACT);     constexpr size_t sX2=12800*4;
constexpr size_t oDOT =AL(oX2+sX2);      constexpr size_t sDOT=12800ull*64*4;
constexpr size_t oAS  =AL(oDOT+sDOT);    constexpr size_t sAS=64ull*12800*2;
constexpr size_t oASUM=AL(oAS+sAS);      constexpr size_t sASUM=512*4;
constexpr size_t oEN  =AL(oASUM+sASUM);  constexpr size_t sEN=8ull*64*256*4;      // raw agg accumulator (f32)
constexpr size_t oENM =AL(oEN+sEN);      constexpr size_t sENM=8*256*4;
constexpr size_t oGAM =AL(oENM+sENM);    constexpr size_t sGAM=8*256*4;
constexpr size_t oH2A =AL(oGAM+sGAM);    constexpr size_t sH2A=8ull*1600*1024*2;  // fc1 out
constexpr size_t oFUSE=AL(oH2A+sH2A);    constexpr size_t sFUSE=8ull*1600*512*2;
constexpr size_t TOTAL_WS=oFUSE+sFUSE;
static_assert(TOTAL_WS < ((size_t)120<<20), "ws layout ~94MB");
// conv split-K partials overlay the dead late-stage region starting at oRRES.
// NOTE: they clobber oEN..oH2A — enraw memset is issued AFTER the partials die.
constexpr size_t oPART =oRRES;             constexpr size_t sPART =4ull*12800*256*4; // 52.4 MB stem
constexpr size_t oPART2=oPART+sPART;       constexpr size_t sPART2=3ull*12800*64*4;  // 9.8 MB cb2
static_assert(oPART2+sPART2<=TOTAL_WS, "partials fit");

// ---------------- weight cast kernels ----------------
struct WCP { const float* s[9]; u16* d[9]; };
__global__ void wcast_plain(WCP p){
  int idx=blockIdx.x*256+threadIdx.x;
  int j,rel;
  if(idx<16384){j=0;rel=idx;}
  else if(idx<32768){j=1;rel=idx-16384;}
  else if(idx<98304){j=2;rel=idx-32768;}
  else if(idx<163840){j=3;rel=idx-98304;}
  else if(idx<229376){j=4;rel=idx-163840;}
  else if(idx<491520){j=5;rel=idx-229376;}
  else if(idx<753664){j=6;rel=idx-491520;}
  else if(idx<884736){j=7;rel=idx-753664;}
  else if(idx<901120){j=8;rel=idx-884736;}
  else return;
  p.d[j][rel]=f2bf(p.s[j][rel]);
}
// stem weights: [co][ci][49] f32 -> [dhw][co][ci] bf16, via LDS transpose.
__global__ void wcast_stem(const float* __restrict__ w, u16* __restrict__ o){
  __shared__ u16 sh[49*256];
  int co=blockIdx.x, ci=threadIdx.x;
  const float* src=w+(size_t)(co*256+ci)*49;
#pragma unroll 7
  for(int j=0;j<49;j++) sh[j*256+ci]=f2bf(src[j]);
  __syncthreads();
#pragma unroll 7
  for(int j=0;j<49;j++) o[((size_t)j*256+co)*256+ci]=sh[j*256+ci];
}
__global__ void wcast_cb2(const float* __restrict__ w, u16* __restrict__ o){
  int idx=blockIdx.x*256+threadIdx.x;           // 9*64*64
  if(idx>=9*4096) return;
  int ci=idx&63; int t=idx>>6; int co=t&63; int dhw=t>>6;
  o[idx]=f2bf(w[(co*64+ci)*9+dhw]);
}
__global__ void c2k(const float* __restrict__ cw, float* __restrict__ c2){
  int k=threadIdx.x; if(k>=64) return;
  float s=0.f;
  for(int i=0;i<256;i++){ float v=cw[k*256+i]; s+=v*v; }
  c2[k]=s;
}

// ---------------- x (NCHW f32) -> xpad (NHWC bf16, pad 3) ----------------
__global__ void x_to_xpad(const float* __restrict__ x, u16* __restrict__ xpad){
  __shared__ u16 sh[40*257];
  int h=blockIdx.x, z=blockIdx.y;
  const float* xb=x+(size_t)z*409600+h*40;
  for(int e=threadIdx.x;e<10240;e+=256){ int c=e/40, w=e-40*(e/40); sh[w*257+c]=f2bf(xb[c*1600+w]); }
  __syncthreads();
  u16* op=xpad+((size_t)(z*46+h+3)*46+3)*256;
  for(int e=threadIdx.x;e<10240;e+=256){ int w=e>>8, c=e&255; op[w*256+c]=sh[w*257+c]; }
}

// ---------------- LDS-staged implicit-GEMM conv, fragment-order staging ----------------
// LDS tile = [group of 16 rows][lane-fragment 16B]: lane l of a gload stages
// global (row=g*16+(l&15), kslot=l>>4) -> compute ds_read is base+ln*16B:
// perfectly linear, ZERO bank conflicts. XSWZ=1: 1D grid, xcd=lin&7 pins one
// (slice,co-block) weight slice per XCD L2.
template<int COT,int COTOT,int PXT,int CIN,int PW,int KS,int NW,int TPS,int TTOT,int NSLICE,int XSWZ>
__global__ __launch_bounds__(NW*64) void conv_lds(
    const u16* __restrict__ Xp, const u16* __restrict__ Wt, float* __restrict__ part){
  constexpr int WPN=PXT/64;          // waves along px
  constexpr int WGR=COT/16;          // W 16-row groups
  constexpr int AGR=PXT/16;          // A 16-row groups
  constexpr int IW=WGR/NW;           // W-group issues per wave
  constexpr int IA=AGR/NW;           // A-group issues per wave
  constexpr int CST=CIN/32;          // k-substeps per tap
  constexpr int CSH=(CST==8)?3:1;

  __shared__ __align__(16) u16 sW[2][COT*32];
  __shared__ __align__(16) u16 sA[2][PXT*32];

  const int wv=threadIdx.x>>6, ln=threadIdx.x&63, lr=ln&15, kg=ln>>4;
  const int wr=wv/WPN, wc=wv%WPN;
  int co0,px0,slice;
  if constexpr(XSWZ){
    int lin=blockIdx.x; int xcd=lin&7, grp=lin>>3;
    slice=xcd>>1; co0=(xcd&1)*COT; px0=grp*PXT;
  } else {
    co0=blockIdx.x*COT; px0=blockIdx.y*PXT; slice=blockIdx.z;
  }
  const int tb=slice*TPS;
  const int te=(slice==NSLICE-1)?TTOT:(tb+TPS);
  const int nst=(te-tb)<<CSH;

  // fragment-order per-lane global source offsets (computed once)
  int wbase[IW], abase[IA];
#pragma unroll
  for(int q=0;q<IW;q++){
    int g=wv*IW+q;
    wbase[q]=(co0+g*16+lr)*CIN+kg*8;
  }
#pragma unroll
  for(int q=0;q<IA;q++){
    int g=wv*IA+q;
    int p=px0+g*16+lr;
    int z=p/1600, rem=p-z*1600;
    int h=rem/40, w=rem-h*40;
    abase[q]=((z*PW+h)*PW+w)*CIN+kg*8;
  }

  f32x4 acc[4][4];
#pragma unroll
  for(int i=0;i<4;i++)
#pragma unroll
    for(int j=0;j<4;j++) acc[i][j]=f32x4{0.f,0.f,0.f,0.f};

  auto stage=[&](int buf,int s){
    int ti=tb+(s>>CSH);
    int c0=(s&(CST-1))<<5;
    int dh=ti/KS, dw=ti-dh*KS;
    const u16* wsrc=Wt+(size_t)ti*COTOT*CIN+c0;
    int aoff=(dh*PW+dw)*CIN+c0;
#pragma unroll
    for(int q=0;q<IW;q++) gload16(wsrc+wbase[q], &sW[buf][(wv*IW+q)*512]);
#pragma unroll
    for(int q=0;q<IA;q++) gload16(Xp+abase[q]+aoff, &sA[buf][(wv*IA+q)*512]);
  };
  auto compute=[&](int buf){
    s16x8 av[4], bv[4];
#pragma unroll
    for(int i=0;i<4;i++) av[i]=*(const s16x8*)(&sW[buf][(wr*4+i)*512+ln*8]);
#pragma unroll
    for(int j=0;j<4;j++) bv[j]=*(const s16x8*)(&sA[buf][(wc*4+j)*512+ln*8]);
#pragma unroll
    for(int i=0;i<4;i++)
#pragma unroll
      for(int j=0;j<4;j++)
        acc[i][j]=__builtin_amdgcn_mfma_f32_16x16x32_bf16(av[i],bv[j],acc[i][j],0,0,0);
  };

  stage(0,0);
  for(int s=0;s<nst;s++){
    __syncthreads();                       // drains prior gloads (vmcnt) + ds reads
    if(s+1<nst) stage((s+1)&1, s+1);
    compute(s&1);
  }

  float* pb=part+(size_t)slice*12800*COTOT;
#pragma unroll
  for(int i=0;i<4;i++){
    int co=co0+wr*64+i*16+kg*4;
#pragma unroll
    for(int j=0;j<4;j++){
      int px=px0+wc*64+j*16+lr;
      *(f32x4*)(pb+(size_t)px*COTOT+co)=acc[i][j];
    }
  }
}

// ---------------- reduce partials + BN + ReLU -> bf16 NHWC ----------------
template<int MT8,int NS>   // MT8 = Ctot/8
__global__ void ep_red(const float* __restrict__ part, const float* __restrict__ g,
    const float* __restrict__ b, u16* __restrict__ out){
  int t=blockIdx.x*256+threadIdx.x;
  int c=(t%MT8)*8; int gp=t/MT8;
  size_t base=(size_t)gp*(MT8*8)+c;
  constexpr size_t SS=(size_t)12800*MT8*8;
  f32x4 v0=*(const f32x4*)(part+base), v1=*(const f32x4*)(part+base+4);
#pragma unroll
  for(int s=1;s<NS;s++){
    f32x4 a0=*(const f32x4*)(part+s*SS+base), a1=*(const f32x4*)(part+s*SS+base+4);
#pragma unroll
    for(int q=0;q<4;q++){ v0[q]+=a0[q]; v1[q]+=a1[q]; }
  }
  u16x8 o;
#pragma unroll
  for(int q=0;q<4;q++) o[q]  =f2bf(fmaxf(v0[q]*g[c+q]  +b[c+q],  0.f));
#pragma unroll
  for(int q=0;q<4;q++) o[4+q]=f2bf(fmaxf(v1[q]*g[c+4+q]+b[c+4+q],0.f));
  *(u16x8*)(out+base)=o;
}

// ---------------- maxpool 3x3 s1 p1 (NHWC bf16) ----------------
__global__ void maxpool3(const u16* __restrict__ in, u16* __restrict__ out){
  int t=blockIdx.x*256+threadIdx.x;
  int c8=(t&31)*8; int gp=t>>5;
  int n=gp%1600; int z=gp/1600; int h=n/40, w=n%40;
  float mx[8];
#pragma unroll
  for(int q=0;q<8;q++) mx[q]=-1e30f;
  for(int dh=-1;dh<=1;dh++){ int hh=h+dh; if((unsigned)hh>=40u) continue;
    for(int dw=-1;dw<=1;dw++){ int ww=w+dw; if((unsigned)ww>=40u) continue;
      u16x8 v=*(const u16x8*)(in+((size_t)z*1600+hh*40+ww)*256+c8);
#pragma unroll
      for(int q=0;q<8;q++) mx[q]=fmaxf(mx[q],bf2f(v[q]));
    }}
  u16x8 o;
#pragma unroll
  for(int q=0;q<8;q++) o[q]=f2bf(mx[q]);
  *(u16x8*)(out+((size_t)z*1600+n)*256+c8)=o;
}

// ---------------- generic NT GEMM: D[m][n] = dot(A[m,:],B[n,:]) + epilogue ----------------
struct GP {
  const u16* A; long long Asz; int lda;
  const u16* Bp; long long Bsz; int ldb;
  int Kd;
  const float *e0,*e1,*e2,*e3;
  const u16* r0;
  u16* ob; float* of; u16* ob2;
  int ldo;
};

template<int MF,int NF,int EPI>
__global__ __launch_bounds__(256) void gemm_nt(GP p){
  const int wv=threadIdx.x>>6, ln=threadIdx.x&63, lr=ln&15, kg=ln>>4;
  int z=blockIdx.z, kc=0;
  if constexpr(EPI==11){ kc=z%5; z=z/5; }        // split-K for aggregation
  const int m0=blockIdx.x*(MF*64)+wv*(MF*16);
  const int n0=blockIdx.y*(NF*16);
  const u16* A=p.A+(size_t)z*p.Asz+kc*320;
  const u16* Bb=p.Bp+(size_t)z*p.Bsz+kc*320;
  const u16* ar[MF]; const u16* br[NF];
#pragma unroll
  for(int i=0;i<MF;i++) ar[i]=A+(size_t)(m0+i*16+lr)*p.lda+kg*8;
#pragma unroll
  for(int j=0;j<NF;j++) br[j]=Bb+(size_t)(n0+j*16+lr)*p.ldb+kg*8;
  f32x4 acc[MF][NF];
#pragma unroll
  for(int i=0;i<MF;i++)
#pragma unroll
    for(int j=0;j<NF;j++) acc[i][j]=f32x4{0.f,0.f,0.f,0.f};
#pragma unroll 2
  for(int k=0;k<p.Kd;k+=32){
    s16x8 av[MF], bv[NF];
#pragma unroll
    for(int i=0;i<MF;i++) av[i]=*(const s16x8*)(ar[i]+k);
#pragma unroll
    for(int j=0;j<NF;j++) bv[j]=*(const s16x8*)(br[j]+k);
#pragma unroll
    for(int i=0;i<MF;i++)
#pragma unroll
      for(int j=0;j<NF;j++)
        acc[i][j]=__builtin_amdgcn_mfma_f32_16x16x32_bf16(av[i],bv[j],acc[i][j],0,0,0);
  }
#pragma unroll
  for(int i=0;i<MF;i++){
    const int mb=m0+i*16+kg*4;
#pragma unroll
    for(int j=0;j<NF;j++){
      const int n=n0+j*16+lr;
      f32x4 v=acc[i][j];
      if constexpr(EPI==1){            // cb1: bn+relu -> padded t1p [42][42][64]
        int h=n/40, w=n%40;
        u16x4 o;
#pragma unroll
        for(int q=0;q<4;q++) o[q]=f2bf(fmaxf(v[q]*p.e0[mb+q]+p.e1[mb+q],0.f));
        *(u16x4*)(p.ob+((size_t)z*1764+(h+1)*42+(w+1))*64+mb)=o;
      } else if constexpr(EPI==2){     // cbres: bn only -> NHWC 256
        u16x4 o;
#pragma unroll
        for(int q=0;q<4;q++) o[q]=f2bf(v[q]*p.e0[mb+q]+p.e1[mb+q]);
        *(u16x4*)(p.ob+((size_t)z*1600+n)*256+mb)=o;
      } else if constexpr(EPI==3){     // cb3: bn + residual + relu -> xc
        u16x4 rv=*(const u16x4*)(p.r0+((size_t)z*1600+n)*256+mb);
        u16x4 o;
#pragma unroll
        for(int q=0;q<4;q++) o[q]=f2bf(fmaxf(v[q]*p.e0[mb+q]+p.e1[mb+q]+bf2f(rv[q]),0.f));
        *(u16x4*)(p.ob+((size_t)z*1600+n)*256+mb)=o;
      } else if constexpr(EPI==4){     // lvc: bn+relu -> z NHWC + zt NCHW
        u16x4 o;
#pragma unroll
        for(int q=0;q<4;q++) o[q]=f2bf(fmaxf(v[q]*p.e0[mb+q]+p.e1[mb+q],0.f));
        *(u16x4*)(p.ob+((size_t)z*1600+n)*256+mb)=o;
#pragma unroll
        for(int q=0;q<4;q++) p.ob2[((size_t)z*256+mb+q)*1600+n]=o[q];
      } else if constexpr(EPI==5){     // dist dot: raw f32 [pix][64]
#pragma unroll
        for(int q=0;q<4;q++) p.of[(size_t)(mb+q)*64+n]=v[q];
      } else if constexpr(EPI==7){     // fc1: gelu(v+bias) -> NHWC ldo
        u16x4 o;
#pragma unroll
        for(int q=0;q<4;q++){ float t=v[q]+p.e0[mb+q]; t=0.5f*t*(1.f+erff(t*0.70710678f)); o[q]=f2bf(t); }
        *(u16x4*)(p.ob+((size_t)z*1600+n)*p.ldo+mb)=o;
      } else if constexpr(EPI==8){     // fc2: xm + ls2*(v+bias) -> fusebuf[:,256:]
        u16x4 rv=*(const u16x4*)(p.r0+((size_t)z*1600+n)*256+mb);
        u16x4 o;
#pragma unroll
        for(int q=0;q<4;q++){ float t=v[q]+p.e0[mb+q]; o[q]=f2bf(bf2f(rv[q])+p.e1[mb+q]*t); }
        *(u16x4*)(p.ob+((size_t)z*1600+n)*512+mb)=o;
      } else if constexpr(EPI==9){     // pw: x1 + ls1*silu(bn(v)) -> xm
        u16x4 rv=*(const u16x4*)(p.r0+((size_t)z*1600+n)*256+mb);
        u16x4 o;
#pragma unroll
        for(int q=0;q<4;q++){ float t=v[q]*p.e0[mb+q]+p.e1[mb+q]; float s=t/(1.f+expf(-t));
          o[q]=f2bf(bf2f(rv[q])+p.e2[mb+q]*s); }
        *(u16x4*)(p.ob+((size_t)z*1600+n)*256+mb)=o;
      } else if constexpr(EPI==10){    // fuse: v + bias -> d_out NCHW f32
#pragma unroll
        for(int q=0;q<4;q++) p.of[((size_t)z*256+mb+q)*1600+n]=v[q]+p.e0[mb+q];
      } else if constexpr(EPI==11){    // aggregation partial: atomic raw f32
#pragma unroll
        for(int q=0;q<4;q++) atomicAdd(&p.of[((size_t)z*64+mb+q)*256+n],v[q]);
      }
    }
  }
}

// ---------------- z row squared-norm ----------------
__global__ void rowsq(const u16* __restrict__ zb, float* __restrict__ x2){
  int wv=threadIdx.x>>6, ln=threadIdx.x&63;
  int gp=blockIdx.x*4+wv;
  u16x4 v=*(const u16x4*)(zb+(size_t)gp*256+ln*4);
  float s=0.f;
#pragma unroll
  for(int q=0;q<4;q++){ float f=bf2f(v[q]); s+=f*f; }
  for(int d=32;d;d>>=1) s+=__shfl_xor(s,d);
  if(ln==0) x2[gp]=s;
}

// ---------------- softmax over 64 codes; store A^T bf16 [k][12800] ----------------
__global__ void softmax_k(const float* __restrict__ dot, const float* __restrict__ x2,
    const float* __restrict__ c2, const float* __restrict__ cws, u16* __restrict__ As){
  int wv=threadIdx.x>>6, ln=threadIdx.x&63;
  int base=blockIdx.x*64+wv*16;
  float sc=cws[ln], cc=c2[ln];
  for(int it=0;it<16;it++){
    int gp=base+it;
    float d=sc*(x2[gp]-2.f*dot[(size_t)gp*64+ln]+cc);
    float m=d;
    for(int o=32;o;o>>=1) m=fmaxf(m,__shfl_xor(m,o));
    float e=expf(d-m);
    float s=e;
    for(int o=32;o;o>>=1) s+=__shfl_xor(s,o);
    As[(size_t)ln*12800+gp]=f2bf(e/s);
  }
}

// ---------------- Asum[b][k] = sum_n A ----------------
__global__ void asum_k(const u16* __restrict__ As, float* __restrict__ Asum){
  int wv=threadIdx.x>>6, ln=threadIdx.x&63;
  int id=blockIdx.x*4+wv;        // 512 = b*64+k
  int b=id>>6, k=id&63;
  const u16* r=As+(size_t)k*12800+b*1600;
  float s=0.f;
  for(int i=ln;i<1600;i+=64) s+=bf2f(r[i]);
  for(int o=32;o;o>>=1) s+=__shfl_xor(s,o);
  if(ln==0) Asum[id]=s;
}

// ---------------- en epilogue (bn1d+relu) fused with mean over codes ----------------
__global__ void enmean_ep(const float* __restrict__ enraw, const float* __restrict__ Asum,
    const float* __restrict__ cw, const float* __restrict__ g, const float* __restrict__ b,
    float* __restrict__ enm){
  int bz=blockIdx.x, c=threadIdx.x;
  float s=0.f;
  for(int k=0;k<64;k++){
    float t=(enraw[((size_t)bz*64+k)*256+c]-Asum[bz*64+k]*cw[k*256+c])*g[k]+b[k];
    s+=fmaxf(t,0.f);
  }
  enm[bz*256+c]=s*(1.f/64.f);
}

// ---------------- fc + sigmoid ----------------
__global__ void fc_sig(const float* __restrict__ enm, const float* __restrict__ wfc,
    const float* __restrict__ bfc, float* __restrict__ gam){
  __shared__ float sh[256];
  int b=blockIdx.x, co=threadIdx.x;
  sh[co]=enm[b*256+co];
  __syncthreads();
  float s=bfc[co];
  for(int i=0;i<256;i++) s+=sh[i]*wfc[co*256+i];
  gam[b*256+co]=1.f/(1.f+expf(-s));
}

// ---------------- x_lvc = relu(xc*(1+gam)) -> fusebuf[:, :256] ----------------
__global__ void ew_xlvc(const u16* __restrict__ xc, const float* __restrict__ gam, u16* __restrict__ fb){
  int t=blockIdx.x*256+threadIdx.x;
  int c=(t&31)*8; int gp=t>>5; int z=gp/1600;
  u16x8 v=*(const u16x8*)(xc+(size_t)gp*256+c);
  u16x8 o;
#pragma unroll
  for(int q=0;q<8;q++){ float ga=1.f+gam[z*256+c+q]; o[q]=f2bf(fmaxf(bf2f(v[q])*ga,0.f)); }
  *(u16x8*)(fb+(size_t)gp*512+c)=o;
}

// ---------------- GN stats (sum, sumsq per batch) ----------------
__global__ void gn_stats(const u16* __restrict__ x, float* __restrict__ st){
  int z=blockIdx.y;
  const u16* pz=x+(size_t)z*409600;
  float s=0.f, ss=0.f;
  for(int i=blockIdx.x*256+threadIdx.x;i<51200;i+=gridDim.x*256){
    u16x8 v=*(const u16x8*)(pz+(size_t)i*8);
#pragma unroll
    for(int q=0;q<8;q++){ float f=bf2f(v[q]); s+=f; ss+=f*f; }
  }
  for(int o=32;o;o>>=1){ s+=__shfl_xor(s,o); ss+=__shfl_xor(ss,o); }
  __shared__ float sh[8];
  int wv=threadIdx.x>>6, ln=threadIdx.x&63;
  if(ln==0){ sh[wv]=s; sh[4+wv]=ss; }
  __syncthreads();
  if(threadIdx.x==0){
    atomicAdd(&st[z*2],  sh[0]+sh[1]+sh[2]+sh[3]);
    atomicAdd(&st[z*2+1],sh[4]+sh[5]+sh[6]+sh[7]);
  }
}

// ---------------- gn1 + dw + bn + silu ----------------
__global__ void ew_hdw(const u16* __restrict__ x1, const float* __restrict__ st,
    const float* __restrict__ g1, const float* __restrict__ b1,
    const float* __restrict__ wdw, const float* __restrict__ gdw, const float* __restrict__ bdw,
    u16* __restrict__ out){
  int t=blockIdx.x*256+threadIdx.x;
  int c=(t&31)*8; int gp=t>>5; int z=gp/1600;
  float mean=st[z*2]*(1.f/409600.f);
  float var=st[z*2+1]*(1.f/409600.f)-mean*mean;
  float rs=rsqrtf(var+1e-5f);
  u16x8 v=*(const u16x8*)(x1+(size_t)gp*256+c);
  u16x8 o;
#pragma unroll
  for(int q=0;q<8;q++){
    int cc=c+q;
    float t0=(bf2f(v[q])-mean)*rs*g1[cc]+b1[cc];
    t0=t0*wdw[cc]*gdw[cc]+bdw[cc];
    o[q]=f2bf(t0/(1.f+expf(-t0)));
  }
  *(u16x8*)(out+(size_t)gp*256+c)=o;
}

// ---------------- gn2 affine only ----------------
__global__ void ew_gn2(const u16* __restrict__ xm, const float* __restrict__ st,
    const float* __restrict__ g2, const float* __restrict__ b2, u16* __restrict__ out){
  int t=blockIdx.x*256+threadIdx.x;
  int c=(t&31)*8; int gp=t>>5; int z=gp/1600;
  float mean=st[z*2]*(1.f/409600.f);
  float var=st[z*2+1]*(1.f/409600.f)-mean*mean;
  float rs=rsqrtf(var+1e-5f);
  u16x8 v=*(const u16x8*)(xm+(size_t)gp*256+c);
  u16x8 o;
#pragma unroll
  for(int q=0;q<8;q++){ int cc=c+q; o[q]=f2bf((bf2f(v[q])-mean)*rs*g2[cc]+b2[cc]); }
  *(u16x8*)(out+(size_t)gp*256+c)=o;
}

// ---------------- launch ----------------
extern "C" void kernel_launch(void* const* d_in, const int* in_sizes, int n_in,
                              void* d_out, int out_size, void* d_ws, size_t ws_size,
                              hipStream_t stream){
  const float* X    =(const float*)d_in[0];
  const float* Wstem=(const float*)d_in[1];
  const float* Gstem=(const float*)d_in[2];
  const float* Bstem=(const float*)d_in[3];
  const float* Wcb1 =(const float*)d_in[4];
  const float* Gcb1 =(const float*)d_in[5];
  const float* Bcb1 =(const float*)d_in[6];
  const float* Wcb2 =(const float*)d_in[7];
  const float* Gcb2 =(const float*)d_in[8];
  const float* Bcb2 =(const float*)d_in[9];
  const float* Wcb3 =(const float*)d_in[10];
  const float* Gcb3 =(const float*)d_in[11];
  const float* Bcb3 =(const float*)d_in[12];
  const float* Wres =(const float*)d_in[13];
  const float* Gres =(const float*)d_in[14];
  const float* Bres =(const float*)d_in[15];
  const float* Wlvc =(const float*)d_in[16];
  const float* Glvc =(const float*)d_in[17];
  const float* Blvc =(const float*)d_in[18];
  const float* CW   =(const float*)d_in[19];
  const float* CWS  =(const float*)d_in[20];
  const float* Genc =(const float*)d_in[21];
  const float* Benc =(const float*)d_in[22];
  const float* Wfc  =(const float*)d_in[23];
  const float* Bfc  =(const float*)d_in[24];
  const float* GN1g =(const float*)d_in[25];
  const float* GN1b =(const float*)d_in[26];
  const float* Wdw  =(const float*)d_in[27];
  const float* Gdw  =(const float*)d_in[28];
  const float* Bdw  =(const float*)d_in[29];
  const float* Wpw  =(const float*)d_in[30];
  const float* Gpw  =(const float*)d_in[31];
  const float* Bpw  =(const float*)d_in[32];
  const float* GN2g =(const float*)d_in[33];
  const float* GN2b =(const float*)d_in[34];
  const float* Wfc1 =(const float*)d_in[35];
  const float* Bfc1 =(const float*)d_in[36];
  const float* Wfc2 =(const float*)d_in[37];
  const float* Bfc2 =(const float*)d_in[38];
  const float* LS1  =(const float*)d_in[39];
  const float* LS2  =(const float*)d_in[40];
  const float* Wcnv =(const float*)d_in[41];
  const float* Bcnv =(const float*)d_in[42];
  char* ws=(char*)d_ws;
  if(ws_size < TOTAL_WS) return;

  u16* xpad=(u16*)(ws+oXPAD);
  u16* t1p =(u16*)(ws+oT1P);
  float* stats=(float*)(ws+oSTAT);
  u16* wst =(u16*)(ws+oWST);
  u16* wcb2t=(u16*)(ws+oWCB2);
  u16* wsm =(u16*)(ws+oWSM);
  float* c2b=(float*)(ws+oC2);
  u16* act =(u16*)(ws+oSTEM);
  u16* x1  =(u16*)(ws+oX1);
  u16* t2  =(u16*)(ws+oT2);
  u16* rres=(u16*)(ws+oRRES);
  u16* xc  =(u16*)(ws+oXC);
  u16* zb  =(u16*)(ws+oZ);
  u16* zt  =(u16*)(ws+oZT);
  float* x2b=(float*)(ws+oX2);
  float* dotb=(float*)(ws+oDOT);
  u16* As  =(u16*)(ws+oAS);
  float* Asum=(float*)(ws+oASUM);
  float* enraw=(float*)(ws+oEN);
  float* enm=(float*)(ws+oENM);
  float* gam=(float*)(ws+oGAM);
  u16* h2a =(u16*)(ws+oH2A);
  u16* fb  =(u16*)(ws+oFUSE);
  u16* xm  =(u16*)(ws+oXPAD);   // reuse (xpad dead after stem)
  u16* xmgn=(u16*)(ws+oWST);    // reuse (stem weights dead after stem)
  u16* hdw =(u16*)(ws+oRRES);   // reuse (rres dead after cb3)
  float* accP =(float*)(ws+oPART);   // stem partials [4][12800][256]
  float* accP2=(float*)(ws+oPART2);  // cb2 partials  [3][12800][64]
  u16* wcb1=wsm+0;      u16* wcb3=wsm+16384;  u16* wresb=wsm+32768; u16* wlvcb=wsm+98304;
  u16* wpwb=wsm+163840; u16* wfc1b=wsm+229376;u16* wfc2b=wsm+491520;u16* wcnvb=wsm+753664;
  u16* cwb=wsm+884736;

  hipMemsetAsync(d_ws,0,ZERO_BYTES,stream);
  { WCP p;
    p.s[0]=Wcb1;p.d[0]=wcb1;  p.s[1]=Wcb3;p.d[1]=wcb3;  p.s[2]=Wres;p.d[2]=wresb;
    p.s[3]=Wlvc;p.d[3]=wlvcb; p.s[4]=Wpw;p.d[4]=wpwb;   p.s[5]=Wfc1;p.d[5]=wfc1b;
    p.s[6]=Wfc2;p.d[6]=wfc2b; p.s[7]=Wcnv;p.d[7]=wcnvb; p.s[8]=CW;p.d[8]=cwb;
    wcast_plain<<<3520,256,0,stream>>>(p); }
  wcast_stem<<<256,256,0,stream>>>(Wstem,wst);
  wcast_cb2<<<144,256,0,stream>>>(Wcb2,wcb2t);
  c2k<<<1,64,0,stream>>>(CW,c2b);
  x_to_xpad<<<dim3(40,8),256,0,stream>>>(X,xpad);

  // stem: XCD-pinned 1D grid (xcd = lin&7 -> (slice,co-block)), frag-order LDS staging
  conv_lds<128,256,128,256,46,7,4,12,49,4,1><<<800,256,0,stream>>>(xpad,wst,accP);
  ep_red<32,4><<<1600,256,0,stream>>>(accP,Gstem,Bstem,act);
  maxpool3<<<1600,256,0,stream>>>(act,x1);

  { GP p{}; p.A=wcb1;p.Asz=0;p.lda=256; p.Bp=x1;p.Bsz=1600*256;p.ldb=256; p.Kd=256;
    p.e0=Gcb1;p.e1=Bcb1; p.ob=t1p;
    gemm_nt<1,4,1><<<dim3(1,25,8),256,0,stream>>>(p); }
  // cb2: LDS-staged conv, split-K over 3 tap groups
  conv_lds<64,64,128,64,42,3,2,3,9,3,0><<<dim3(1,100,3),128,0,stream>>>(t1p,wcb2t,accP2);
  ep_red<8,3><<<400,256,0,stream>>>(accP2,Gcb2,Bcb2,t2);
  { GP p{}; p.A=wresb;p.Asz=0;p.lda=256; p.Bp=x1;p.Bsz=1600*256;p.ldb=256; p.Kd=256;
    p.e0=Gres;p.e1=Bres; p.ob=rres;
    gemm_nt<1,4,2><<<dim3(4,25,8),256,0,stream>>>(p); }
  { GP p{}; p.A=wcb3;p.Asz=0;p.lda=64; p.Bp=t2;p.Bsz=1600*64;p.ldb=64; p.Kd=64;
    p.e0=Gcb3;p.e1=Bcb3; p.r0=rres; p.ob=xc;
    gemm_nt<1,4,3><<<dim3(4,25,8),256,0,stream>>>(p); }
  { GP p{}; p.A=wlvcb;p.Asz=0;p.lda=256; p.Bp=xc;p.Bsz=1600*256;p.ldb=256; p.Kd=256;
    p.e0=Glvc;p.e1=Blvc; p.ob=zb; p.ob2=zt;
    gemm_nt<1,4,4><<<dim3(4,25,8),256,0,stream>>>(p); }
  rowsq<<<3200,256,0,stream>>>(zb,x2b);
  { GP p{}; p.A=zb;p.Asz=0;p.lda=256; p.Bp=cwb;p.Bsz=0;p.ldb=256; p.Kd=256; p.of=dotb;
    gemm_nt<1,4,5><<<dim3(200,1,1),256,0,stream>>>(p); }
  softmax_k<<<200,256,0,stream>>>(dotb,x2b,c2b,CWS,As);
  asum_k<<<128,256,0,stream>>>(As,Asum);
  // enraw region was clobbered by conv partials -> zero it here (partials are dead now)
  hipMemsetAsync(enraw,0,sEN,stream);
  // aggregation: split-K (5 chunks of 320 pixels) with raw f32 atomics
  { GP p{}; p.A=As;p.Asz=1600;p.lda=12800; p.Bp=zt;p.Bsz=256*1600;p.ldb=1600; p.Kd=320;
    p.of=enraw;
    gemm_nt<1,4,11><<<dim3(1,4,40),256,0,stream>>>(p); }
  enmean_ep<<<8,256,0,stream>>>(enraw,Asum,CW,Genc,Benc,enm);
  fc_sig<<<8,256,0,stream>>>(enm,Wfc,Bfc,gam);
  ew_xlvc<<<1600,256,0,stream>>>(xc,gam,fb);

  gn_stats<<<dim3(25,8),256,0,stream>>>(x1,stats);
  ew_hdw<<<1600,256,0,stream>>>(x1,stats,GN1g,GN1b,Wdw,Gdw,Bdw,hdw);
  { GP p{}; p.A=wpwb;p.Asz=0;p.lda=256; p.Bp=hdw;p.Bsz=1600*256;p.ldb=256; p.Kd=256;
    p.e0=Gpw;p.e1=Bpw;p.e2=LS1; p.r0=x1; p.ob=xm;
    gemm_nt<1,4,9><<<dim3(4,25,8),256,0,stream>>>(p); }
  gn_stats<<<dim3(25,8),256,0,stream>>>(xm,stats+16);
  ew_gn2<<<1600,256,0,stream>>>(xm,stats+16,GN2g,GN2b,xmgn);
  { GP p{}; p.A=wfc1b;p.Asz=0;p.lda=256; p.Bp=xmgn;p.Bsz=1600*256;p.ldb=256; p.Kd=256;
    p.e0=Bfc1; p.ob=h2a; p.ldo=1024;
    gemm_nt<1,4,7><<<dim3(16,25,8),256,0,stream>>>(p); }
  { GP p{}; p.A=wfc2b;p.Asz=0;p.lda=1024; p.Bp=h2a;p.Bsz=1600*1024;p.ldb=1024; p.Kd=1024;
    p.e0=Bfc2;p.e1=LS2; p.r0=xm; p.ob=fb+256;
    gemm_nt<1,4,8><<<dim3(4,25,8),256,0,stream>>>(p); }
  { GP p{}; p.A=wcnvb;p.Asz=0;p.lda=512; p.Bp=fb;p.Bsz=1600*512;p.ldb=512; p.Kd=512;
    p.e0=Bcnv; p.of=(float*)d_out;
    gemm_nt<1,4,10><<<dim3(4,25,8),256,0,stream>>>(p); }
}

// Round 7
// 718.109 us; speedup vs baseline: 1.0803x; 1.0803x over previous
//
#include <hip/hip_runtime.h>
#include <hip/hip_bf16.h>
#include <math.h>

typedef unsigned short u16;
typedef u16 u16x4 __attribute__((ext_vector_type(4)));
typedef u16 u16x8 __attribute__((ext_vector_type(8)));
typedef short s16x8 __attribute__((ext_vector_type(8)));
typedef float f32x4 __attribute__((ext_vector_type(4)));

#define DEVI static __device__ __forceinline__

DEVI float bf2f(u16 u){ unsigned v=((unsigned)u)<<16; float f; __builtin_memcpy(&f,&v,4); return f; }
DEVI u16 f2bf(float f){ unsigned u; __builtin_memcpy(&u,&f,4); u=(u+0x7FFFu+((u>>16)&1u))>>16; return (u16)u; }

// async global->LDS, 16B per lane. LDS dest must be wave-uniform base (lane scatter
// comes from the per-lane GLOBAL address -> fragment-order pre-permutation).
DEVI void gload16(const u16* g, u16* l){
  __builtin_amdgcn_global_load_lds(
      (const __attribute__((address_space(1))) void*)(unsigned long long)g,
      (__attribute__((address_space(3))) void*)(unsigned int)(unsigned long long)l,
      16, 0, 0);
}

// ---------------- workspace layout (bytes) ----------------
constexpr size_t AL(size_t x){ return (x+511)&~(size_t)511; }
constexpr size_t sACT =8ull*1600*256*2;                       // one NHWC bf16 activation (6.55 MB)
constexpr size_t oXPAD=0;                constexpr size_t sXPAD=8ull*46*46*256*2; // stem padded input; reused as xm
constexpr size_t oT1P =AL(oXPAD+sXPAD);  constexpr size_t sT1P=8ull*42*42*64*2;   // cb1 out, padded
constexpr size_t oSTAT=AL(oT1P+sT1P);    constexpr size_t sSTAT=512;              // gn1[16]+gn2[16] floats
constexpr size_t ZERO_BYTES=oSTAT+sSTAT;
constexpr size_t oWST =AL(ZERO_BYTES);   constexpr size_t sWST=6553600;           // stem w bf16 [49][256][256]; reused as xmgn
constexpr size_t oWCB2=AL(oWST+sWST);    constexpr size_t sWCB2=9*64*64*2;
constexpr size_t oWSM =AL(oWCB2+sWCB2);  constexpr size_t sWSM=901120ull*2;       // all 1x1 weights bf16
constexpr size_t oC2  =AL(oWSM+sWSM);    constexpr size_t sC2=1024;
constexpr size_t oSTEM=AL(oC2+sC2);                                                // stem conv out
constexpr size_t oX1  =AL(oSTEM+sACT);
constexpr size_t oT2  =AL(oX1+sACT);     constexpr size_t sT2=8ull*1600*64*2;
constexpr size_t oRRES=AL(oT2+sT2);                                                // cbres out; reused as hdw + conv partials
constexpr size_t oXC  =AL(oRRES+sACT);
constexpr size_t oZ   =AL(oXC+sACT);
constexpr size_t oZT  =AL(oZ+sACT);                                                // z transposed NCHW
constexpr size_t oX2  =AL(oZT+sACT);     constexpr size_t sX2=12800*4;
constexpr size_t oDOT =AL(oX2+sX2);      constexpr size_t sDOT=12800ull*64*4;
constexpr size_t oAS  =AL(oDOT+sDOT);    constexpr size_t sAS=64ull*12800*2;
constexpr size_t oASUM=AL(oAS+sAS);      constexpr size_t sASUM=512*4;
constexpr size_t oEN  =AL(oASUM+sASUM);  constexpr size_t sEN=8ull*64*256*4;      // raw agg accumulator (f32)
constexpr size_t oENM =AL(oEN+sEN);      constexpr size_t sENM=8*256*4;
constexpr size_t oGAM =AL(oENM+sENM);    constexpr size_t sGAM=8*256*4;
constexpr size_t oH2A =AL(oGAM+sGAM);    constexpr size_t sH2A=8ull*1600*1024*2;  // fc1 out
constexpr size_t oFUSE=AL(oH2A+sH2A);    constexpr size_t sFUSE=8ull*1600*512*2;
constexpr size_t TOTAL_WS=oFUSE+sFUSE;
static_assert(TOTAL_WS < ((size_t)120<<20), "ws layout ~94MB");
// conv split-K partials overlay the dead late-stage region starting at oRRES.
// NOTE: they clobber oEN..oH2A — enraw memset is issued AFTER the partials die.
constexpr size_t oPART =oRRES;             constexpr size_t sPART =4ull*12800*256*4; // 52.4 MB stem
constexpr size_t oPART2=oPART+sPART;       constexpr size_t sPART2=3ull*12800*64*4;  // 9.8 MB cb2
static_assert(oPART2+sPART2<=TOTAL_WS, "partials fit");

// ---------------- weight cast kernels ----------------
struct WCP { const float* s[9]; u16* d[9]; };
__global__ void wcast_plain(WCP p){
  int idx=blockIdx.x*256+threadIdx.x;
  int j,rel;
  if(idx<16384){j=0;rel=idx;}
  else if(idx<32768){j=1;rel=idx-16384;}
  else if(idx<98304){j=2;rel=idx-32768;}
  else if(idx<163840){j=3;rel=idx-98304;}
  else if(idx<229376){j=4;rel=idx-163840;}
  else if(idx<491520){j=5;rel=idx-229376;}
  else if(idx<753664){j=6;rel=idx-491520;}
  else if(idx<884736){j=7;rel=idx-753664;}
  else if(idx<901120){j=8;rel=idx-884736;}
  else return;
  p.d[j][rel]=f2bf(p.s[j][rel]);
}
// stem weights: [co][ci][49] f32 -> [dhw][co][ci] bf16, via LDS transpose.
__global__ void wcast_stem(const float* __restrict__ w, u16* __restrict__ o){
  __shared__ u16 sh[49*256];
  int co=blockIdx.x, ci=threadIdx.x;
  const float* src=w+(size_t)(co*256+ci)*49;
#pragma unroll 7
  for(int j=0;j<49;j++) sh[j*256+ci]=f2bf(src[j]);
  __syncthreads();
#pragma unroll 7
  for(int j=0;j<49;j++) o[((size_t)j*256+co)*256+ci]=sh[j*256+ci];
}
__global__ void wcast_cb2(const float* __restrict__ w, u16* __restrict__ o){
  int idx=blockIdx.x*256+threadIdx.x;           // 9*64*64
  if(idx>=9*4096) return;
  int ci=idx&63; int t=idx>>6; int co=t&63; int dhw=t>>6;
  o[idx]=f2bf(w[(co*64+ci)*9+dhw]);
}
__global__ void c2k(const float* __restrict__ cw, float* __restrict__ c2){
  int k=threadIdx.x; if(k>=64) return;
  float s=0.f;
  for(int i=0;i<256;i++){ float v=cw[k*256+i]; s+=v*v; }
  c2[k]=s;
}

// ---------------- x (NCHW f32) -> xpad (NHWC bf16, pad 3) ----------------
__global__ void x_to_xpad(const float* __restrict__ x, u16* __restrict__ xpad){
  __shared__ u16 sh[40*257];
  int h=blockIdx.x, z=blockIdx.y;
  const float* xb=x+(size_t)z*409600+h*40;
  for(int e=threadIdx.x;e<10240;e+=256){ int c=e/40, w=e-40*(e/40); sh[w*257+c]=f2bf(xb[c*1600+w]); }
  __syncthreads();
  u16* op=xpad+((size_t)(z*46+h+3)*46+3)*256;
  for(int e=threadIdx.x;e<10240;e+=256){ int w=e>>8, c=e&255; op[w*256+c]=sh[w*257+c]; }
}

// ---------------- LDS-staged implicit-GEMM conv, fragment-order staging ----------------
// LDS tile = [group of 16 rows][lane-fragment 16B]: lane l of a gload stages
// global (row=g*16+(l&15), kslot=l>>4) -> compute ds_read is base+ln*16B:
// perfectly linear, ZERO bank conflicts (verified r5: conflicts 1e7 -> 0).
// XSWZ=1: PIXEL-STATIONARY XCD pinning: xcd=lin&7 = contiguous px chunk (13
// tiles = 1.15 MB activation window, L2-fits); all 8 (slice,co) combos for the
// chunk land on the same XCD so the 96 tap-substep re-reads hit L2; weights
// stream once per XCD (6.4MB x 8 = 51 MB HBM).
template<int COT,int COTOT,int PXT,int CIN,int PW,int KS,int NW,int TPS,int TTOT,int NSLICE,int XSWZ>
__global__ __launch_bounds__(NW*64) void conv_lds(
    const u16* __restrict__ Xp, const u16* __restrict__ Wt, float* __restrict__ part){
  constexpr int WPN=PXT/64;          // waves along px
  constexpr int WGR=COT/16;          // W 16-row groups
  constexpr int AGR=PXT/16;          // A 16-row groups
  constexpr int IW=WGR/NW;           // W-group issues per wave
  constexpr int IA=AGR/NW;           // A-group issues per wave
  constexpr int CST=CIN/32;          // k-substeps per tap
  constexpr int CSH=(CST==8)?3:1;

  __shared__ __align__(16) u16 sW[2][COT*32];
  __shared__ __align__(16) u16 sA[2][PXT*32];

  const int wv=threadIdx.x>>6, ln=threadIdx.x&63, lr=ln&15, kg=ln>>4;
  const int wr=wv/WPN, wc=wv%WPN;
  int co0,px0,slice;
  if constexpr(XSWZ){
    int lin=blockIdx.x; int xcd=lin&7, rest=lin>>3;   // rest 0..103
    int combo=rest/13, pxin=rest%13;
    int pxt=xcd*13+pxin;
    if(pxt>=100) return;                              // ragged chunk guard
    slice=combo>>1; co0=(combo&1)*COT; px0=pxt*PXT;
  } else {
    co0=blockIdx.x*COT; px0=blockIdx.y*PXT; slice=blockIdx.z;
  }
  const int tb=slice*TPS;
  const int te=(slice==NSLICE-1)?TTOT:(tb+TPS);
  const int nst=(te-tb)<<CSH;

  // fragment-order per-lane global source offsets (computed once)
  int wbase[IW], abase[IA];
#pragma unroll
  for(int q=0;q<IW;q++){
    int g=wv*IW+q;
    wbase[q]=(co0+g*16+lr)*CIN+kg*8;
  }
#pragma unroll
  for(int q=0;q<IA;q++){
    int g=wv*IA+q;
    int p=px0+g*16+lr;
    int z=p/1600, rem=p-z*1600;
    int h=rem/40, w=rem-h*40;
    abase[q]=((z*PW+h)*PW+w)*CIN+kg*8;
  }

  f32x4 acc[4][4];
#pragma unroll
  for(int i=0;i<4;i++)
#pragma unroll
    for(int j=0;j<4;j++) acc[i][j]=f32x4{0.f,0.f,0.f,0.f};

  auto stage=[&](int buf,int s){
    int ti=tb+(s>>CSH);
    int c0=(s&(CST-1))<<5;
    int dh=ti/KS, dw=ti-dh*KS;
    const u16* wsrc=Wt+(size_t)ti*COTOT*CIN+c0;
    int aoff=(dh*PW+dw)*CIN+c0;
#pragma unroll
    for(int q=0;q<IW;q++) gload16(wsrc+wbase[q], &sW[buf][(wv*IW+q)*512]);
#pragma unroll
    for(int q=0;q<IA;q++) gload16(Xp+abase[q]+aoff, &sA[buf][(wv*IA+q)*512]);
  };
  auto compute=[&](int buf){
    s16x8 av[4], bv[4];
#pragma unroll
    for(int i=0;i<4;i++) av[i]=*(const s16x8*)(&sW[buf][(wr*4+i)*512+ln*8]);
#pragma unroll
    for(int j=0;j<4;j++) bv[j]=*(const s16x8*)(&sA[buf][(wc*4+j)*512+ln*8]);
#pragma unroll
    for(int i=0;i<4;i++)
#pragma unroll
      for(int j=0;j<4;j++)
        acc[i][j]=__builtin_amdgcn_mfma_f32_16x16x32_bf16(av[i],bv[j],acc[i][j],0,0,0);
  };

  stage(0,0);
  for(int s=0;s<nst;s++){
    __syncthreads();                       // drains prior gloads (vmcnt) + ds reads
    if(s+1<nst) stage((s+1)&1, s+1);
    compute(s&1);
  }

  float* pb=part+(size_t)slice*12800*COTOT;
#pragma unroll
  for(int i=0;i<4;i++){
    int co=co0+wr*64+i*16+kg*4;
#pragma unroll
    for(int j=0;j<4;j++){
      int px=px0+wc*64+j*16+lr;
      *(f32x4*)(pb+(size_t)px*COTOT+co)=acc[i][j];
    }
  }
}

// ---------------- reduce partials + BN + ReLU -> bf16 NHWC ----------------
template<int MT8,int NS>   // MT8 = Ctot/8
__global__ void ep_red(const float* __restrict__ part, const float* __restrict__ g,
    const float* __restrict__ b, u16* __restrict__ out){
  int t=blockIdx.x*256+threadIdx.x;
  int c=(t%MT8)*8; int gp=t/MT8;
  size_t base=(size_t)gp*(MT8*8)+c;
  constexpr size_t SS=(size_t)12800*MT8*8;
  f32x4 v0=*(const f32x4*)(part+base), v1=*(const f32x4*)(part+base+4);
#pragma unroll
  for(int s=1;s<NS;s++){
    f32x4 a0=*(const f32x4*)(part+s*SS+base), a1=*(const f32x4*)(part+s*SS+base+4);
#pragma unroll
    for(int q=0;q<4;q++){ v0[q]+=a0[q]; v1[q]+=a1[q]; }
  }
  u16x8 o;
#pragma unroll
  for(int q=0;q<4;q++) o[q]  =f2bf(fmaxf(v0[q]*g[c+q]  +b[c+q],  0.f));
#pragma unroll
  for(int q=0;q<4;q++) o[4+q]=f2bf(fmaxf(v1[q]*g[c+4+q]+b[c+4+q],0.f));
  *(u16x8*)(out+base)=o;
}

// ---------------- maxpool 3x3 s1 p1 (NHWC bf16) ----------------
__global__ void maxpool3(const u16* __restrict__ in, u16* __restrict__ out){
  int t=blockIdx.x*256+threadIdx.x;
  int c8=(t&31)*8; int gp=t>>5;
  int n=gp%1600; int z=gp/1600; int h=n/40, w=n%40;
  float mx[8];
#pragma unroll
  for(int q=0;q<8;q++) mx[q]=-1e30f;
  for(int dh=-1;dh<=1;dh++){ int hh=h+dh; if((unsigned)hh>=40u) continue;
    for(int dw=-1;dw<=1;dw++){ int ww=w+dw; if((unsigned)ww>=40u) continue;
      u16x8 v=*(const u16x8*)(in+((size_t)z*1600+hh*40+ww)*256+c8);
#pragma unroll
      for(int q=0;q<8;q++) mx[q]=fmaxf(mx[q],bf2f(v[q]));
    }}
  u16x8 o;
#pragma unroll
  for(int q=0;q<8;q++) o[q]=f2bf(mx[q]);
  *(u16x8*)(out+((size_t)z*1600+n)*256+c8)=o;
}

// ---------------- generic NT GEMM: D[m][n] = dot(A[m,:],B[n,:]) + epilogue ----------------
struct GP {
  const u16* A; long long Asz; int lda;
  const u16* Bp; long long Bsz; int ldb;
  int Kd;
  const float *e0,*e1,*e2,*e3;
  const u16* r0;
  u16* ob; float* of; u16* ob2;
  int ldo;
};

template<int MF,int NF,int EPI>
__global__ __launch_bounds__(256) void gemm_nt(GP p){
  const int wv=threadIdx.x>>6, ln=threadIdx.x&63, lr=ln&15, kg=ln>>4;
  int z=blockIdx.z, kc=0;
  if constexpr(EPI==11){ kc=z%5; z=z/5; }        // split-K for aggregation
  const int m0=blockIdx.x*(MF*64)+wv*(MF*16);
  const int n0=blockIdx.y*(NF*16);
  const u16* A=p.A+(size_t)z*p.Asz+kc*320;
  const u16* Bb=p.Bp+(size_t)z*p.Bsz+kc*320;
  const u16* ar[MF]; const u16* br[NF];
#pragma unroll
  for(int i=0;i<MF;i++) ar[i]=A+(size_t)(m0+i*16+lr)*p.lda+kg*8;
#pragma unroll
  for(int j=0;j<NF;j++) br[j]=Bb+(size_t)(n0+j*16+lr)*p.ldb+kg*8;
  f32x4 acc[MF][NF];
#pragma unroll
  for(int i=0;i<MF;i++)
#pragma unroll
    for(int j=0;j<NF;j++) acc[i][j]=f32x4{0.f,0.f,0.f,0.f};
  for(int k=0;k<p.Kd;k+=32){
    s16x8 av[MF], bv[NF];
#pragma unroll
    for(int i=0;i<MF;i++) av[i]=*(const s16x8*)(ar[i]+k);
#pragma unroll
    for(int j=0;j<NF;j++) bv[j]=*(const s16x8*)(br[j]+k);
#pragma unroll
    for(int i=0;i<MF;i++)
#pragma unroll
      for(int j=0;j<NF;j++)
        acc[i][j]=__builtin_amdgcn_mfma_f32_16x16x32_bf16(av[i],bv[j],acc[i][j],0,0,0);
  }
#pragma unroll
  for(int i=0;i<MF;i++){
    const int mb=m0+i*16+kg*4;
#pragma unroll
    for(int j=0;j<NF;j++){
      const int n=n0+j*16+lr;
      f32x4 v=acc[i][j];
      if constexpr(EPI==1){            // cb1: bn+relu -> padded t1p [42][42][64]
        int h=n/40, w=n%40;
        u16x4 o;
#pragma unroll
        for(int q=0;q<4;q++) o[q]=f2bf(fmaxf(v[q]*p.e0[mb+q]+p.e1[mb+q],0.f));
        *(u16x4*)(p.ob+((size_t)z*1764+(h+1)*42+(w+1))*64+mb)=o;
      } else if constexpr(EPI==2){     // cbres: bn only -> NHWC 256
        u16x4 o;
#pragma unroll
        for(int q=0;q<4;q++) o[q]=f2bf(v[q]*p.e0[mb+q]+p.e1[mb+q]);
        *(u16x4*)(p.ob+((size_t)z*1600+n)*256+mb)=o;
      } else if constexpr(EPI==3){     // cb3: bn + residual + relu -> xc
        u16x4 rv=*(const u16x4*)(p.r0+((size_t)z*1600+n)*256+mb);
        u16x4 o;
#pragma unroll
        for(int q=0;q<4;q++) o[q]=f2bf(fmaxf(v[q]*p.e0[mb+q]+p.e1[mb+q]+bf2f(rv[q]),0.f));
        *(u16x4*)(p.ob+((size_t)z*1600+n)*256+mb)=o;
      } else if constexpr(EPI==4){     // lvc: bn+relu -> z NHWC + zt NCHW
        u16x4 o;
#pragma unroll
        for(int q=0;q<4;q++) o[q]=f2bf(fmaxf(v[q]*p.e0[mb+q]+p.e1[mb+q],0.f));
        *(u16x4*)(p.ob+((size_t)z*1600+n)*256+mb)=o;
#pragma unroll
        for(int q=0;q<4;q++) p.ob2[((size_t)z*256+mb+q)*1600+n]=o[q];
      } else if constexpr(EPI==5){     // dist dot: raw f32 [pix][64]
#pragma unroll
        for(int q=0;q<4;q++) p.of[(size_t)(mb+q)*64+n]=v[q];
      } else if constexpr(EPI==7){     // fc1: gelu(v+bias) -> NHWC ldo
        u16x4 o;
#pragma unroll
        for(int q=0;q<4;q++){ float t=v[q]+p.e0[mb+q]; t=0.5f*t*(1.f+erff(t*0.70710678f)); o[q]=f2bf(t); }
        *(u16x4*)(p.ob+((size_t)z*1600+n)*p.ldo+mb)=o;
      } else if constexpr(EPI==8){     // fc2: xm + ls2*(v+bias) -> fusebuf[:,256:]
        u16x4 rv=*(const u16x4*)(p.r0+((size_t)z*1600+n)*256+mb);
        u16x4 o;
#pragma unroll
        for(int q=0;q<4;q++){ float t=v[q]+p.e0[mb+q]; o[q]=f2bf(bf2f(rv[q])+p.e1[mb+q]*t); }
        *(u16x4*)(p.ob+((size_t)z*1600+n)*512+mb)=o;
      } else if constexpr(EPI==9){     // pw: x1 + ls1*silu(bn(v)) -> xm
        u16x4 rv=*(const u16x4*)(p.r0+((size_t)z*1600+n)*256+mb);
        u16x4 o;
#pragma unroll
        for(int q=0;q<4;q++){ float t=v[q]*p.e0[mb+q]+p.e1[mb+q]; float s=t/(1.f+expf(-t));
          o[q]=f2bf(bf2f(rv[q])+p.e2[mb+q]*s); }
        *(u16x4*)(p.ob+((size_t)z*1600+n)*256+mb)=o;
      } else if constexpr(EPI==10){    // fuse: v + bias -> d_out NCHW f32
#pragma unroll
        for(int q=0;q<4;q++) p.of[((size_t)z*256+mb+q)*1600+n]=v[q]+p.e0[mb+q];
      } else if constexpr(EPI==11){    // aggregation partial: atomic raw f32
#pragma unroll
        for(int q=0;q<4;q++) atomicAdd(&p.of[((size_t)z*64+mb+q)*256+n],v[q]);
      }
    }
  }
}

// ---------------- z row squared-norm ----------------
__global__ void rowsq(const u16* __restrict__ zb, float* __restrict__ x2){
  int wv=threadIdx.x>>6, ln=threadIdx.x&63;
  int gp=blockIdx.x*4+wv;
  u16x4 v=*(const u16x4*)(zb+(size_t)gp*256+ln*4);
  float s=0.f;
#pragma unroll
  for(int q=0;q<4;q++){ float f=bf2f(v[q]); s+=f*f; }
  for(int d=32;d;d>>=1) s+=__shfl_xor(s,d);
  if(ln==0) x2[gp]=s;
}

// ---------------- softmax over 64 codes; store A^T bf16 [k][12800] ----------------
__global__ void softmax_k(const float* __restrict__ dot, const float* __restrict__ x2,
    const float* __restrict__ c2, const float* __restrict__ cws, u16* __restrict__ As){
  int wv=threadIdx.x>>6, ln=threadIdx.x&63;
  int base=blockIdx.x*64+wv*16;
  float sc=cws[ln], cc=c2[ln];
  for(int it=0;it<16;it++){
    int gp=base+it;
    float d=sc*(x2[gp]-2.f*dot[(size_t)gp*64+ln]+cc);
    float m=d;
    for(int o=32;o;o>>=1) m=fmaxf(m,__shfl_xor(m,o));
    float e=expf(d-m);
    float s=e;
    for(int o=32;o;o>>=1) s+=__shfl_xor(s,o);
    As[(size_t)ln*12800+gp]=f2bf(e/s);
  }
}

// ---------------- Asum[b][k] = sum_n A ----------------
__global__ void asum_k(const u16* __restrict__ As, float* __restrict__ Asum){
  int wv=threadIdx.x>>6, ln=threadIdx.x&63;
  int id=blockIdx.x*4+wv;        // 512 = b*64+k
  int b=id>>6, k=id&63;
  const u16* r=As+(size_t)k*12800+b*1600;
  float s=0.f;
  for(int i=ln;i<1600;i+=64) s+=bf2f(r[i]);
  for(int o=32;o;o>>=1) s+=__shfl_xor(s,o);
  if(ln==0) Asum[id]=s;
}

// ---------------- en epilogue (bn1d+relu) fused with mean over codes ----------------
__global__ void enmean_ep(const float* __restrict__ enraw, const float* __restrict__ Asum,
    const float* __restrict__ cw, const float* __restrict__ g, const float* __restrict__ b,
    float* __restrict__ enm){
  int bz=blockIdx.x, c=threadIdx.x;
  float s=0.f;
  for(int k=0;k<64;k++){
    float t=(enraw[((size_t)bz*64+k)*256+c]-Asum[bz*64+k]*cw[k*256+c])*g[k]+b[k];
    s+=fmaxf(t,0.f);
  }
  enm[bz*256+c]=s*(1.f/64.f);
}

// ---------------- fc + sigmoid ----------------
__global__ void fc_sig(const float* __restrict__ enm, const float* __restrict__ wfc,
    const float* __restrict__ bfc, float* __restrict__ gam){
  __shared__ float sh[256];
  int b=blockIdx.x, co=threadIdx.x;
  sh[co]=enm[b*256+co];
  __syncthreads();
  float s=bfc[co];
  for(int i=0;i<256;i++) s+=sh[i]*wfc[co*256+i];
  gam[b*256+co]=1.f/(1.f+expf(-s));
}

// ---------------- x_lvc = relu(xc*(1+gam)) -> fusebuf[:, :256] ----------------
__global__ void ew_xlvc(const u16* __restrict__ xc, const float* __restrict__ gam, u16* __restrict__ fb){
  int t=blockIdx.x*256+threadIdx.x;
  int c=(t&31)*8; int gp=t>>5; int z=gp/1600;
  u16x8 v=*(const u16x8*)(xc+(size_t)gp*256+c);
  u16x8 o;
#pragma unroll
  for(int q=0;q<8;q++){ float ga=1.f+gam[z*256+c+q]; o[q]=f2bf(fmaxf(bf2f(v[q])*ga,0.f)); }
  *(u16x8*)(fb+(size_t)gp*512+c)=o;
}

// ---------------- GN stats (sum, sumsq per batch) ----------------
__global__ void gn_stats(const u16* __restrict__ x, float* __restrict__ st){
  int z=blockIdx.y;
  const u16* pz=x+(size_t)z*409600;
  float s=0.f, ss=0.f;
  for(int i=blockIdx.x*256+threadIdx.x;i<51200;i+=gridDim.x*256){
    u16x8 v=*(const u16x8*)(pz+(size_t)i*8);
#pragma unroll
    for(int q=0;q<8;q++){ float f=bf2f(v[q]); s+=f; ss+=f*f; }
  }
  for(int o=32;o;o>>=1){ s+=__shfl_xor(s,o); ss+=__shfl_xor(ss,o); }
  __shared__ float sh[8];
  int wv=threadIdx.x>>6, ln=threadIdx.x&63;
  if(ln==0){ sh[wv]=s; sh[4+wv]=ss; }
  __syncthreads();
  if(threadIdx.x==0){
    atomicAdd(&st[z*2],  sh[0]+sh[1]+sh[2]+sh[3]);
    atomicAdd(&st[z*2+1],sh[4]+sh[5]+sh[6]+sh[7]);
  }
}

// ---------------- gn1 + dw + bn + silu ----------------
__global__ void ew_hdw(const u16* __restrict__ x1, const float* __restrict__ st,
    const float* __restrict__ g1, const float* __restrict__ b1,
    const float* __restrict__ wdw, const float* __restrict__ gdw, const float* __restrict__ bdw,
    u16* __restrict__ out){
  int t=blockIdx.x*256+threadIdx.x;
  int c=(t&31)*8; int gp=t>>5; int z=gp/1600;
  float mean=st[z*2]*(1.f/409600.f);
  float var=st[z*2+1]*(1.f/409600.f)-mean*mean;
  float rs=rsqrtf(var+1e-5f);
  u16x8 v=*(const u16x8*)(x1+(size_t)gp*256+c);
  u16x8 o;
#pragma unroll
  for(int q=0;q<8;q++){
    int cc=c+q;
    float t0=(bf2f(v[q])-mean)*rs*g1[cc]+b1[cc];
    t0=t0*wdw[cc]*gdw[cc]+bdw[cc];
    o[q]=f2bf(t0/(1.f+expf(-t0)));
  }
  *(u16x8*)(out+(size_t)gp*256+c)=o;
}

// ---------------- gn2 affine only ----------------
__global__ void ew_gn2(const u16* __restrict__ xm, const float* __restrict__ st,
    const float* __restrict__ g2, const float* __restrict__ b2, u16* __restrict__ out){
  int t=blockIdx.x*256+threadIdx.x;
  int c=(t&31)*8; int gp=t>>5; int z=gp/1600;
  float mean=st[z*2]*(1.f/409600.f);
  float var=st[z*2+1]*(1.f/409600.f)-mean*mean;
  float rs=rsqrtf(var+1e-5f);
  u16x8 v=*(const u16x8*)(xm+(size_t)gp*256+c);
  u16x8 o;
#pragma unroll
  for(int q=0;q<8;q++){ int cc=c+q; o[q]=f2bf((bf2f(v[q])-mean)*rs*g2[cc]+b2[cc]); }
  *(u16x8*)(out+(size_t)gp*256+c)=o;
}

// ---------------- launch ----------------
extern "C" void kernel_launch(void* const* d_in, const int* in_sizes, int n_in,
                              void* d_out, int out_size, void* d_ws, size_t ws_size,
                              hipStream_t stream){
  const float* X    =(const float*)d_in[0];
  const float* Wstem=(const float*)d_in[1];
  const float* Gstem=(const float*)d_in[2];
  const float* Bstem=(const float*)d_in[3];
  const float* Wcb1 =(const float*)d_in[4];
  const float* Gcb1 =(const float*)d_in[5];
  const float* Bcb1 =(const float*)d_in[6];
  const float* Wcb2 =(const float*)d_in[7];
  const float* Gcb2 =(const float*)d_in[8];
  const float* Bcb2 =(const float*)d_in[9];
  const float* Wcb3 =(const float*)d_in[10];
  const float* Gcb3 =(const float*)d_in[11];
  const float* Bcb3 =(const float*)d_in[12];
  const float* Wres =(const float*)d_in[13];
  const float* Gres =(const float*)d_in[14];
  const float* Bres =(const float*)d_in[15];
  const float* Wlvc =(const float*)d_in[16];
  const float* Glvc =(const float*)d_in[17];
  const float* Blvc =(const float*)d_in[18];
  const float* CW   =(const float*)d_in[19];
  const float* CWS  =(const float*)d_in[20];
  const float* Genc =(const float*)d_in[21];
  const float* Benc =(const float*)d_in[22];
  const float* Wfc  =(const float*)d_in[23];
  const float* Bfc  =(const float*)d_in[24];
  const float* GN1g =(const float*)d_in[25];
  const float* GN1b =(const float*)d_in[26];
  const float* Wdw  =(const float*)d_in[27];
  const float* Gdw  =(const float*)d_in[28];
  const float* Bdw  =(const float*)d_in[29];
  const float* Wpw  =(const float*)d_in[30];
  const float* Gpw  =(const float*)d_in[31];
  const float* Bpw  =(const float*)d_in[32];
  const float* GN2g =(const float*)d_in[33];
  const float* GN2b =(const float*)d_in[34];
  const float* Wfc1 =(const float*)d_in[35];
  const float* Bfc1 =(const float*)d_in[36];
  const float* Wfc2 =(const float*)d_in[37];
  const float* Bfc2 =(const float*)d_in[38];
  const float* LS1  =(const float*)d_in[39];
  const float* LS2  =(const float*)d_in[40];
  const float* Wcnv =(const float*)d_in[41];
  const float* Bcnv =(const float*)d_in[42];
  char* ws=(char*)d_ws;
  if(ws_size < TOTAL_WS) return;

  u16* xpad=(u16*)(ws+oXPAD);
  u16* t1p =(u16*)(ws+oT1P);
  float* stats=(float*)(ws+oSTAT);
  u16* wst =(u16*)(ws+oWST);
  u16* wcb2t=(u16*)(ws+oWCB2);
  u16* wsm =(u16*)(ws+oWSM);
  float* c2b=(float*)(ws+oC2);
  u16* act =(u16*)(ws+oSTEM);
  u16* x1  =(u16*)(ws+oX1);
  u16* t2  =(u16*)(ws+oT2);
  u16* rres=(u16*)(ws+oRRES);
  u16* xc  =(u16*)(ws+oXC);
  u16* zb  =(u16*)(ws+oZ);
  u16* zt  =(u16*)(ws+oZT);
  float* x2b=(float*)(ws+oX2);
  float* dotb=(float*)(ws+oDOT);
  u16* As  =(u16*)(ws+oAS);
  float* Asum=(float*)(ws+oASUM);
  float* enraw=(float*)(ws+oEN);
  float* enm=(float*)(ws+oENM);
  float* gam=(float*)(ws+oGAM);
  u16* h2a =(u16*)(ws+oH2A);
  u16* fb  =(u16*)(ws+oFUSE);
  u16* xm  =(u16*)(ws+oXPAD);   // reuse (xpad dead after stem)
  u16* xmgn=(u16*)(ws+oWST);    // reuse (stem weights dead after stem)
  u16* hdw =(u16*)(ws+oRRES);   // reuse (rres dead after cb3)
  float* accP =(float*)(ws+oPART);   // stem partials [4][12800][256]
  float* accP2=(float*)(ws+oPART2);  // cb2 partials  [3][12800][64]
  u16* wcb1=wsm+0;      u16* wcb3=wsm+16384;  u16* wresb=wsm+32768; u16* wlvcb=wsm+98304;
  u16* wpwb=wsm+163840; u16* wfc1b=wsm+229376;u16* wfc2b=wsm+491520;u16* wcnvb=wsm+753664;
  u16* cwb=wsm+884736;

  hipMemsetAsync(d_ws,0,ZERO_BYTES,stream);
  { WCP p;
    p.s[0]=Wcb1;p.d[0]=wcb1;  p.s[1]=Wcb3;p.d[1]=wcb3;  p.s[2]=Wres;p.d[2]=wresb;
    p.s[3]=Wlvc;p.d[3]=wlvcb; p.s[4]=Wpw;p.d[4]=wpwb;   p.s[5]=Wfc1;p.d[5]=wfc1b;
    p.s[6]=Wfc2;p.d[6]=wfc2b; p.s[7]=Wcnv;p.d[7]=wcnvb; p.s[8]=CW;p.d[8]=cwb;
    wcast_plain<<<3520,256,0,stream>>>(p); }
  wcast_stem<<<256,256,0,stream>>>(Wstem,wst);
  wcast_cb2<<<144,256,0,stream>>>(Wcb2,wcb2t);
  c2k<<<1,64,0,stream>>>(CW,c2b);
  x_to_xpad<<<dim3(40,8),256,0,stream>>>(X,xpad);

  // stem: pixel-stationary XCD pinning (xcd=lin&7 = px chunk), frag-order staging
  conv_lds<128,256,128,256,46,7,4,12,49,4,1><<<832,256,0,stream>>>(xpad,wst,accP);
  ep_red<32,4><<<1600,256,0,stream>>>(accP,Gstem,Bstem,act);
  maxpool3<<<1600,256,0,stream>>>(act,x1);

  { GP p{}; p.A=wcb1;p.Asz=0;p.lda=256; p.Bp=x1;p.Bsz=1600*256;p.ldb=256; p.Kd=256;
    p.e0=Gcb1;p.e1=Bcb1; p.ob=t1p;
    gemm_nt<1,5,1><<<dim3(1,20,8),256,0,stream>>>(p); }
  // cb2: LDS-staged conv, split-K over 3 tap groups
  conv_lds<64,64,128,64,42,3,2,3,9,3,0><<<dim3(1,100,3),128,0,stream>>>(t1p,wcb2t,accP2);
  ep_red<8,3><<<400,256,0,stream>>>(accP2,Gcb2,Bcb2,t2);
  { GP p{}; p.A=wresb;p.Asz=0;p.lda=256; p.Bp=x1;p.Bsz=1600*256;p.ldb=256; p.Kd=256;
    p.e0=Gres;p.e1=Bres; p.ob=rres;
    gemm_nt<2,5,2><<<dim3(2,20,8),256,0,stream>>>(p); }
  { GP p{}; p.A=wcb3;p.Asz=0;p.lda=64; p.Bp=t2;p.Bsz=1600*64;p.ldb=64; p.Kd=64;
    p.e0=Gcb3;p.e1=Bcb3; p.r0=rres; p.ob=xc;
    gemm_nt<2,5,3><<<dim3(2,20,8),256,0,stream>>>(p); }
  { GP p{}; p.A=wlvcb;p.Asz=0;p.lda=256; p.Bp=xc;p.Bsz=1600*256;p.ldb=256; p.Kd=256;
    p.e0=Glvc;p.e1=Blvc; p.ob=zb; p.ob2=zt;
    gemm_nt<2,5,4><<<dim3(2,20,8),256,0,stream>>>(p); }
  rowsq<<<3200,256,0,stream>>>(zb,x2b);
  { GP p{}; p.A=zb;p.Asz=0;p.lda=256; p.Bp=cwb;p.Bsz=0;p.ldb=256; p.Kd=256; p.of=dotb;
    gemm_nt<2,4,5><<<dim3(100,1,1),256,0,stream>>>(p); }
  softmax_k<<<200,256,0,stream>>>(dotb,x2b,c2b,CWS,As);
  asum_k<<<128,256,0,stream>>>(As,Asum);
  // enraw region was clobbered by conv partials -> zero it here (partials are dead now)
  hipMemsetAsync(enraw,0,sEN,stream);
  // aggregation: split-K (5 chunks of 320 pixels) with raw f32 atomics
  { GP p{}; p.A=As;p.Asz=1600;p.lda=12800; p.Bp=zt;p.Bsz=256*1600;p.ldb=1600; p.Kd=320;
    p.of=enraw;
    gemm_nt<1,4,11><<<dim3(1,4,40),256,0,stream>>>(p); }
  enmean_ep<<<8,256,0,stream>>>(enraw,Asum,CW,Genc,Benc,enm);
  fc_sig<<<8,256,0,stream>>>(enm,Wfc,Bfc,gam);
  ew_xlvc<<<1600,256,0,stream>>>(xc,gam,fb);

  gn_stats<<<dim3(25,8),256,0,stream>>>(x1,stats);
  ew_hdw<<<1600,256,0,stream>>>(x1,stats,GN1g,GN1b,Wdw,Gdw,Bdw,hdw);
  { GP p{}; p.A=wpwb;p.Asz=0;p.lda=256; p.Bp=hdw;p.Bsz=1600*256;p.ldb=256; p.Kd=256;
    p.e0=Gpw;p.e1=Bpw;p.e2=LS1; p.r0=x1; p.ob=xm;
    gemm_nt<2,5,9><<<dim3(2,20,8),256,0,stream>>>(p); }
  gn_stats<<<dim3(25,8),256,0,stream>>>(xm,stats+16);
  ew_gn2<<<1600,256,0,stream>>>(xm,stats+16,GN2g,GN2b,xmgn);
  { GP p{}; p.A=wfc1b;p.Asz=0;p.lda=256; p.Bp=xmgn;p.Bsz=1600*256;p.ldb=256; p.Kd=256;
    p.e0=Bfc1; p.ob=h2a; p.ldo=1024;
    gemm_nt<2,5,7><<<dim3(8,20,8),256,0,stream>>>(p); }
  { GP p{}; p.A=wfc2b;p.Asz=0;p.lda=1024; p.Bp=h2a;p.Bsz=1600*1024;p.ldb=1024; p.Kd=1024;
    p.e0=Bfc2;p.e1=LS2; p.r0=xm; p.ob=fb+256;
    gemm_nt<2,5,8><<<dim3(2,20,8),256,0,stream>>>(p); }
  { GP p{}; p.A=wcnvb;p.Asz=0;p.lda=512; p.Bp=fb;p.Bsz=1600*512;p.ldb=512; p.Kd=512;
    p.e0=Bcnv; p.of=(float*)d_out;
    gemm_nt<2,5,10><<<dim3(2,20,8),256,0,stream>>>(p); }
}

// Round 8
// 709.529 us; speedup vs baseline: 1.0933x; 1.0121x over previous
//
#include <hip/hip_runtime.h>
#include <hip/hip_bf16.h>
#include <math.h>

typedef unsigned short u16;
typedef u16 u16x4 __attribute__((ext_vector_type(4)));
typedef u16 u16x8 __attribute__((ext_vector_type(8)));
typedef short s16x8 __attribute__((ext_vector_type(8)));
typedef float f32x4 __attribute__((ext_vector_type(4)));

#define DEVI static __device__ __forceinline__

DEVI float bf2f(u16 u){ unsigned v=((unsigned)u)<<16; float f; __builtin_memcpy(&f,&v,4); return f; }
DEVI u16 f2bf(float f){ unsigned u; __builtin_memcpy(&u,&f,4); u=(u+0x7FFFu+((u>>16)&1u))>>16; return (u16)u; }

// async global->LDS, 16B per lane. LDS dest must be wave-uniform base (lane scatter
// comes from the per-lane GLOBAL address -> fragment-order pre-permutation).
DEVI void gload16(const u16* g, u16* l){
  __builtin_amdgcn_global_load_lds(
      (const __attribute__((address_space(1))) void*)(unsigned long long)g,
      (__attribute__((address_space(3))) void*)(unsigned int)(unsigned long long)l,
      16, 0, 0);
}

// ---------------- workspace layout (bytes) ----------------
constexpr size_t AL(size_t x){ return (x+511)&~(size_t)511; }
constexpr size_t sACT =8ull*1600*256*2;                       // one NHWC bf16 activation (6.55 MB)
constexpr size_t oXPAD=0;                constexpr size_t sXPAD=8ull*46*46*256*2; // stem padded input; reused as xm
constexpr size_t oT1P =AL(oXPAD+sXPAD);  constexpr size_t sT1P=8ull*42*42*64*2;   // cb1 out, padded
constexpr size_t oSTAT=AL(oT1P+sT1P);    constexpr size_t sSTAT=512;              // gn1[16]+gn2[16] floats
constexpr size_t ZERO_BYTES=oSTAT+sSTAT;
constexpr size_t oWST =AL(ZERO_BYTES);   constexpr size_t sWST=6553600;           // stem w bf16 [49][256][256]; reused as xmgn
constexpr size_t oWCB2=AL(oWST+sWST);    constexpr size_t sWCB2=9*64*64*2;
constexpr size_t oWSM =AL(oWCB2+sWCB2);  constexpr size_t sWSM=901120ull*2;       // all 1x1 weights bf16
constexpr size_t oC2  =AL(oWSM+sWSM);    constexpr size_t sC2=1024;
constexpr size_t oSTEM=AL(oC2+sC2);                                                // stem conv out
constexpr size_t oX1  =AL(oSTEM+sACT);
constexpr size_t oT2  =AL(oX1+sACT);     constexpr size_t sT2=8ull*1600*64*2;
constexpr size_t oRRES=AL(oT2+sT2);                                                // cbres out; reused as hdw + conv partials
constexpr size_t oXC  =AL(oRRES+sACT);
constexpr size_t oZ   =AL(oXC+sACT);
constexpr size_t oZT  =AL(oZ+sACT);                                                // z transposed NCHW
constexpr size_t oX2  =AL(oZT+sACT);     constexpr size_t sX2=12800*4;
constexpr size_t oDOT =AL(oX2+sX2);      constexpr size_t sDOT=12800ull*64*4;
constexpr size_t oAS  =AL(oDOT+sDOT);    constexpr size_t sAS=64ull*12800*2;
constexpr size_t oASUM=AL(oAS+sAS);      constexpr size_t sASUM=512*4;
constexpr size_t oEN  =AL(oASUM+sASUM);  constexpr size_t sEN=8ull*64*256*4;      // raw agg accumulator (f32)
constexpr size_t oENM =AL(oEN+sEN);      constexpr size_t sENM=8*256*4;
constexpr size_t oGAM =AL(oENM+sENM);    constexpr size_t sGAM=8*256*4;
constexpr size_t oH2A =AL(oGAM+sGAM);    constexpr size_t sH2A=8ull*1600*1024*2;  // fc1 out
constexpr size_t oFUSE=AL(oH2A+sH2A);    constexpr size_t sFUSE=8ull*1600*512*2;
constexpr size_t TOTAL_WS=oFUSE+sFUSE;
static_assert(TOTAL_WS < ((size_t)120<<20), "ws layout ~94MB");
// conv split-K partials (bf16) overlay the dead late-stage region starting at oRRES.
// NOTE: they clobber oEN..into oH2A — enraw memset is issued AFTER the partials die.
constexpr size_t oPART =oRRES;             constexpr size_t sPART =7ull*12800*256*2; // 45.9 MB stem bf16
constexpr size_t oPART2=oPART+sPART;       constexpr size_t sPART2=3ull*12800*64*2;  // 4.9 MB cb2 bf16
static_assert(oPART2+sPART2<=TOTAL_WS, "partials fit");

// ---------------- weight cast kernels ----------------
struct WCP { const float* s[9]; u16* d[9]; };
__global__ void wcast_plain(WCP p){
  int idx=blockIdx.x*256+threadIdx.x;
  int j,rel;
  if(idx<16384){j=0;rel=idx;}
  else if(idx<32768){j=1;rel=idx-16384;}
  else if(idx<98304){j=2;rel=idx-32768;}
  else if(idx<163840){j=3;rel=idx-98304;}
  else if(idx<229376){j=4;rel=idx-163840;}
  else if(idx<491520){j=5;rel=idx-229376;}
  else if(idx<753664){j=6;rel=idx-491520;}
  else if(idx<884736){j=7;rel=idx-753664;}
  else if(idx<901120){j=8;rel=idx-884736;}
  else return;
  p.d[j][rel]=f2bf(p.s[j][rel]);
}
// stem weights: [co][ci][49] f32 -> [dhw][co][ci] bf16, via LDS transpose.
__global__ void wcast_stem(const float* __restrict__ w, u16* __restrict__ o){
  __shared__ u16 sh[49*256];
  int co=blockIdx.x, ci=threadIdx.x;
  const float* src=w+(size_t)(co*256+ci)*49;
#pragma unroll 7
  for(int j=0;j<49;j++) sh[j*256+ci]=f2bf(src[j]);
  __syncthreads();
#pragma unroll 7
  for(int j=0;j<49;j++) o[((size_t)j*256+co)*256+ci]=sh[j*256+ci];
}
__global__ void wcast_cb2(const float* __restrict__ w, u16* __restrict__ o){
  int idx=blockIdx.x*256+threadIdx.x;           // 9*64*64
  if(idx>=9*4096) return;
  int ci=idx&63; int t=idx>>6; int co=t&63; int dhw=t>>6;
  o[idx]=f2bf(w[(co*64+ci)*9+dhw]);
}
__global__ void c2k(const float* __restrict__ cw, float* __restrict__ c2){
  int k=threadIdx.x; if(k>=64) return;
  float s=0.f;
  for(int i=0;i<256;i++){ float v=cw[k*256+i]; s+=v*v; }
  c2[k]=s;
}

// ---------------- x (NCHW f32) -> xpad (NHWC bf16, pad 3) ----------------
__global__ void x_to_xpad(const float* __restrict__ x, u16* __restrict__ xpad){
  __shared__ u16 sh[40*257];
  int h=blockIdx.x, z=blockIdx.y;
  const float* xb=x+(size_t)z*409600+h*40;
  for(int e=threadIdx.x;e<10240;e+=256){ int c=e/40, w=e-40*(e/40); sh[w*257+c]=f2bf(xb[c*1600+w]); }
  __syncthreads();
  u16* op=xpad+((size_t)(z*46+h+3)*46+3)*256;
  for(int e=threadIdx.x;e<10240;e+=256){ int w=e>>8, c=e&255; op[w*256+c]=sh[w*257+c]; }
}

// ---------------- LDS-staged implicit-GEMM conv, fragment-order staging ----------------
// LDS tile = [group of 16 rows][lane-fragment 16B]: zero bank conflicts (r5-verified).
// Partials stored bf16 (f32 accum in regs; f32 reduce in ep_red) -> 7 slices fit,
// grid 1456 blocks (~5.5/CU work, 5 resident by LDS) for latency hiding.
// XSWZ=1: pixel-stationary XCD pinning (r7-verified FETCH 312->35MB).
template<int COT,int COTOT,int PXT,int CIN,int PW,int KS,int NW,int TPS,int TTOT,int NSLICE,int XSWZ>
__global__ __launch_bounds__(NW*64) void conv_lds(
    const u16* __restrict__ Xp, const u16* __restrict__ Wt, u16* __restrict__ part){
  constexpr int WPN=PXT/64;          // waves along px
  constexpr int WGR=COT/16;          // W 16-row groups
  constexpr int AGR=PXT/16;          // A 16-row groups
  constexpr int IW=WGR/NW;           // W-group issues per wave
  constexpr int IA=AGR/NW;           // A-group issues per wave
  constexpr int CST=CIN/32;          // k-substeps per tap
  constexpr int CSH=(CST==8)?3:1;

  __shared__ __align__(16) u16 sW[2][COT*32];
  __shared__ __align__(16) u16 sA[2][PXT*32];

  const int wv=threadIdx.x>>6, ln=threadIdx.x&63, lr=ln&15, kg=ln>>4;
  const int wr=wv/WPN, wc=wv%WPN;
  int co0,px0,slice;
  if constexpr(XSWZ){
    int lin=blockIdx.x; int xcd=lin&7, rest=lin>>3;   // rest 0..181
    int combo=rest/13, pxin=rest%13;                  // combo 0..13 = (slice,coblk)
    int pxt=xcd*13+pxin;
    if(pxt>=100) return;                              // ragged chunk guard
    slice=combo>>1; co0=(combo&1)*COT; px0=pxt*PXT;
  } else {
    co0=blockIdx.x*COT; px0=blockIdx.y*PXT; slice=blockIdx.z;
  }
  const int tb=slice*TPS;
  const int te=(slice==NSLICE-1)?TTOT:(tb+TPS);
  const int nst=(te-tb)<<CSH;

  // fragment-order per-lane global source offsets (computed once)
  int wbase[IW], abase[IA];
#pragma unroll
  for(int q=0;q<IW;q++){
    int g=wv*IW+q;
    wbase[q]=(co0+g*16+lr)*CIN+kg*8;
  }
#pragma unroll
  for(int q=0;q<IA;q++){
    int g=wv*IA+q;
    int p=px0+g*16+lr;
    int z=p/1600, rem=p-z*1600;
    int h=rem/40, w=rem-h*40;
    abase[q]=((z*PW+h)*PW+w)*CIN+kg*8;
  }

  f32x4 acc[4][4];
#pragma unroll
  for(int i=0;i<4;i++)
#pragma unroll
    for(int j=0;j<4;j++) acc[i][j]=f32x4{0.f,0.f,0.f,0.f};

  auto stage=[&](int buf,int s){
    int ti=tb+(s>>CSH);
    int c0=(s&(CST-1))<<5;
    int dh=ti/KS, dw=ti-dh*KS;
    const u16* wsrc=Wt+(size_t)ti*COTOT*CIN+c0;
    int aoff=(dh*PW+dw)*CIN+c0;
#pragma unroll
    for(int q=0;q<IW;q++) gload16(wsrc+wbase[q], &sW[buf][(wv*IW+q)*512]);
#pragma unroll
    for(int q=0;q<IA;q++) gload16(Xp+abase[q]+aoff, &sA[buf][(wv*IA+q)*512]);
  };
  auto compute=[&](int buf){
    s16x8 av[4], bv[4];
#pragma unroll
    for(int i=0;i<4;i++) av[i]=*(const s16x8*)(&sW[buf][(wr*4+i)*512+ln*8]);
#pragma unroll
    for(int j=0;j<4;j++) bv[j]=*(const s16x8*)(&sA[buf][(wc*4+j)*512+ln*8]);
#pragma unroll
    for(int i=0;i<4;i++)
#pragma unroll
      for(int j=0;j<4;j++)
        acc[i][j]=__builtin_amdgcn_mfma_f32_16x16x32_bf16(av[i],bv[j],acc[i][j],0,0,0);
  };

  stage(0,0);
  for(int s=0;s<nst;s++){
    __syncthreads();                       // drains prior gloads (vmcnt) + ds reads
    if(s+1<nst) stage((s+1)&1, s+1);
    compute(s&1);
  }

  u16* pb=part+(size_t)slice*12800*COTOT;
#pragma unroll
  for(int i=0;i<4;i++){
    int co=co0+wr*64+i*16+kg*4;
#pragma unroll
    for(int j=0;j<4;j++){
      int px=px0+wc*64+j*16+lr;
      u16x4 o;
#pragma unroll
      for(int q=0;q<4;q++) o[q]=f2bf(acc[i][j][q]);
      *(u16x4*)(pb+(size_t)px*COTOT+co)=o;
    }
  }
}

// ---------------- reduce bf16 partials + BN + ReLU -> bf16 NHWC ----------------
template<int MT8,int NS>   // MT8 = Ctot/8
__global__ void ep_red(const u16* __restrict__ part, const float* __restrict__ g,
    const float* __restrict__ b, u16* __restrict__ out){
  int t=blockIdx.x*256+threadIdx.x;
  int c=(t%MT8)*8; int gp=t/MT8;
  size_t base=(size_t)gp*(MT8*8)+c;
  constexpr size_t SS=(size_t)12800*MT8*8;
  float v[8];
#pragma unroll
  for(int q=0;q<8;q++) v[q]=0.f;
#pragma unroll
  for(int s=0;s<NS;s++){
    u16x8 a=*(const u16x8*)(part+s*SS+base);
#pragma unroll
    for(int q=0;q<8;q++) v[q]+=bf2f(a[q]);
  }
  u16x8 o;
#pragma unroll
  for(int q=0;q<8;q++) o[q]=f2bf(fmaxf(v[q]*g[c+q]+b[c+q],0.f));
  *(u16x8*)(out+base)=o;
}

// ---------------- maxpool 3x3 s1 p1 (NHWC bf16) ----------------
__global__ void maxpool3(const u16* __restrict__ in, u16* __restrict__ out){
  int t=blockIdx.x*256+threadIdx.x;
  int c8=(t&31)*8; int gp=t>>5;
  int n=gp%1600; int z=gp/1600; int h=n/40, w=n%40;
  float mx[8];
#pragma unroll
  for(int q=0;q<8;q++) mx[q]=-1e30f;
  for(int dh=-1;dh<=1;dh++){ int hh=h+dh; if((unsigned)hh>=40u) continue;
    for(int dw=-1;dw<=1;dw++){ int ww=w+dw; if((unsigned)ww>=40u) continue;
      u16x8 v=*(const u16x8*)(in+((size_t)z*1600+hh*40+ww)*256+c8);
#pragma unroll
      for(int q=0;q<8;q++) mx[q]=fmaxf(mx[q],bf2f(v[q]));
    }}
  u16x8 o;
#pragma unroll
  for(int q=0;q<8;q++) o[q]=f2bf(mx[q]);
  *(u16x8*)(out+((size_t)z*1600+n)*256+c8)=o;
}

// ---------------- generic NT GEMM: D[m][n] = dot(A[m,:],B[n,:]) + epilogue ----------------
// K-loop unrolled 2x with both load sets issued before MFMAs (14 loads in flight).
struct GP {
  const u16* A; long long Asz; int lda;
  const u16* Bp; long long Bsz; int ldb;
  int Kd;
  const float *e0,*e1,*e2,*e3;
  const u16* r0;
  u16* ob; float* of; u16* ob2;
  int ldo;
};

template<int MF,int NF,int EPI>
__global__ __launch_bounds__(256) void gemm_nt(GP p){
  const int wv=threadIdx.x>>6, ln=threadIdx.x&63, lr=ln&15, kg=ln>>4;
  int z=blockIdx.z, kc=0;
  if constexpr(EPI==11){ kc=z%5; z=z/5; }        // split-K for aggregation
  const int m0=blockIdx.x*(MF*64)+wv*(MF*16);
  const int n0=blockIdx.y*(NF*16);
  const u16* A=p.A+(size_t)z*p.Asz+kc*320;
  const u16* Bb=p.Bp+(size_t)z*p.Bsz+kc*320;
  const u16* ar[MF]; const u16* br[NF];
#pragma unroll
  for(int i=0;i<MF;i++) ar[i]=A+(size_t)(m0+i*16+lr)*p.lda+kg*8;
#pragma unroll
  for(int j=0;j<NF;j++) br[j]=Bb+(size_t)(n0+j*16+lr)*p.ldb+kg*8;
  f32x4 acc[MF][NF];
#pragma unroll
  for(int i=0;i<MF;i++)
#pragma unroll
    for(int j=0;j<NF;j++) acc[i][j]=f32x4{0.f,0.f,0.f,0.f};
  int k=0;
  for(;k+64<=p.Kd;k+=64){
    s16x8 av0[MF], bv0[NF], av1[MF], bv1[NF];
#pragma unroll
    for(int i=0;i<MF;i++){ av0[i]=*(const s16x8*)(ar[i]+k); av1[i]=*(const s16x8*)(ar[i]+k+32); }
#pragma unroll
    for(int j=0;j<NF;j++){ bv0[j]=*(const s16x8*)(br[j]+k); bv1[j]=*(const s16x8*)(br[j]+k+32); }
#pragma unroll
    for(int i=0;i<MF;i++)
#pragma unroll
      for(int j=0;j<NF;j++)
        acc[i][j]=__builtin_amdgcn_mfma_f32_16x16x32_bf16(av0[i],bv0[j],acc[i][j],0,0,0);
#pragma unroll
    for(int i=0;i<MF;i++)
#pragma unroll
      for(int j=0;j<NF;j++)
        acc[i][j]=__builtin_amdgcn_mfma_f32_16x16x32_bf16(av1[i],bv1[j],acc[i][j],0,0,0);
  }
  for(;k<p.Kd;k+=32){
    s16x8 av[MF], bv[NF];
#pragma unroll
    for(int i=0;i<MF;i++) av[i]=*(const s16x8*)(ar[i]+k);
#pragma unroll
    for(int j=0;j<NF;j++) bv[j]=*(const s16x8*)(br[j]+k);
#pragma unroll
    for(int i=0;i<MF;i++)
#pragma unroll
      for(int j=0;j<NF;j++)
        acc[i][j]=__builtin_amdgcn_mfma_f32_16x16x32_bf16(av[i],bv[j],acc[i][j],0,0,0);
  }
#pragma unroll
  for(int i=0;i<MF;i++){
    const int mb=m0+i*16+kg*4;
#pragma unroll
    for(int j=0;j<NF;j++){
      const int n=n0+j*16+lr;
      f32x4 v=acc[i][j];
      if constexpr(EPI==1){            // cb1: bn+relu -> padded t1p [42][42][64]
        int h=n/40, w=n%40;
        u16x4 o;
#pragma unroll
        for(int q=0;q<4;q++) o[q]=f2bf(fmaxf(v[q]*p.e0[mb+q]+p.e1[mb+q],0.f));
        *(u16x4*)(p.ob+((size_t)z*1764+(h+1)*42+(w+1))*64+mb)=o;
      } else if constexpr(EPI==2){     // cbres: bn only -> NHWC 256
        u16x4 o;
#pragma unroll
        for(int q=0;q<4;q++) o[q]=f2bf(v[q]*p.e0[mb+q]+p.e1[mb+q]);
        *(u16x4*)(p.ob+((size_t)z*1600+n)*256+mb)=o;
      } else if constexpr(EPI==3){     // cb3: bn + residual + relu -> xc
        u16x4 rv=*(const u16x4*)(p.r0+((size_t)z*1600+n)*256+mb);
        u16x4 o;
#pragma unroll
        for(int q=0;q<4;q++) o[q]=f2bf(fmaxf(v[q]*p.e0[mb+q]+p.e1[mb+q]+bf2f(rv[q]),0.f));
        *(u16x4*)(p.ob+((size_t)z*1600+n)*256+mb)=o;
      } else if constexpr(EPI==4){     // lvc: bn+relu -> z NHWC + zt NCHW
        u16x4 o;
#pragma unroll
        for(int q=0;q<4;q++) o[q]=f2bf(fmaxf(v[q]*p.e0[mb+q]+p.e1[mb+q],0.f));
        *(u16x4*)(p.ob+((size_t)z*1600+n)*256+mb)=o;
#pragma unroll
        for(int q=0;q<4;q++) p.ob2[((size_t)z*256+mb+q)*1600+n]=o[q];
      } else if constexpr(EPI==5){     // dist dot: raw f32 [pix][64]
#pragma unroll
        for(int q=0;q<4;q++) p.of[(size_t)(mb+q)*64+n]=v[q];
      } else if constexpr(EPI==7){     // fc1: gelu(v+bias) -> NHWC ldo
        u16x4 o;
#pragma unroll
        for(int q=0;q<4;q++){ float t=v[q]+p.e0[mb+q]; t=0.5f*t*(1.f+erff(t*0.70710678f)); o[q]=f2bf(t); }
        *(u16x4*)(p.ob+((size_t)z*1600+n)*p.ldo+mb)=o;
      } else if constexpr(EPI==8){     // fc2: xm + ls2*(v+bias) -> fusebuf[:,256:]
        u16x4 rv=*(const u16x4*)(p.r0+((size_t)z*1600+n)*256+mb);
        u16x4 o;
#pragma unroll
        for(int q=0;q<4;q++){ float t=v[q]+p.e0[mb+q]; o[q]=f2bf(bf2f(rv[q])+p.e1[mb+q]*t); }
        *(u16x4*)(p.ob+((size_t)z*1600+n)*512+mb)=o;
      } else if constexpr(EPI==9){     // pw: x1 + ls1*silu(bn(v)) -> xm
        u16x4 rv=*(const u16x4*)(p.r0+((size_t)z*1600+n)*256+mb);
        u16x4 o;
#pragma unroll
        for(int q=0;q<4;q++){ float t=v[q]*p.e0[mb+q]+p.e1[mb+q]; float s=t/(1.f+expf(-t));
          o[q]=f2bf(bf2f(rv[q])+p.e2[mb+q]*s); }
        *(u16x4*)(p.ob+((size_t)z*1600+n)*256+mb)=o;
      } else if constexpr(EPI==10){    // fuse: v + bias -> d_out NCHW f32
#pragma unroll
        for(int q=0;q<4;q++) p.of[((size_t)z*256+mb+q)*1600+n]=v[q]+p.e0[mb+q];
      } else if constexpr(EPI==11){    // aggregation partial: atomic raw f32
#pragma unroll
        for(int q=0;q<4;q++) atomicAdd(&p.of[((size_t)z*64+mb+q)*256+n],v[q]);
      }
    }
  }
}

// ---------------- z row squared-norm ----------------
__global__ void rowsq(const u16* __restrict__ zb, float* __restrict__ x2){
  int wv=threadIdx.x>>6, ln=threadIdx.x&63;
  int gp=blockIdx.x*4+wv;
  u16x4 v=*(const u16x4*)(zb+(size_t)gp*256+ln*4);
  float s=0.f;
#pragma unroll
  for(int q=0;q<4;q++){ float f=bf2f(v[q]); s+=f*f; }
  for(int d=32;d;d>>=1) s+=__shfl_xor(s,d);
  if(ln==0) x2[gp]=s;
}

// ---------------- softmax over 64 codes; store A^T bf16 [k][12800] ----------------
__global__ void softmax_k(const float* __restrict__ dot, const float* __restrict__ x2,
    const float* __restrict__ c2, const float* __restrict__ cws, u16* __restrict__ As){
  int wv=threadIdx.x>>6, ln=threadIdx.x&63;
  int base=blockIdx.x*64+wv*16;
  float sc=cws[ln], cc=c2[ln];
  for(int it=0;it<16;it++){
    int gp=base+it;
    float d=sc*(x2[gp]-2.f*dot[(size_t)gp*64+ln]+cc);
    float m=d;
    for(int o=32;o;o>>=1) m=fmaxf(m,__shfl_xor(m,o));
    float e=expf(d-m);
    float s=e;
    for(int o=32;o;o>>=1) s+=__shfl_xor(s,o);
    As[(size_t)ln*12800+gp]=f2bf(e/s);
  }
}

// ---------------- Asum[b][k] = sum_n A ----------------
__global__ void asum_k(const u16* __restrict__ As, float* __restrict__ Asum){
  int wv=threadIdx.x>>6, ln=threadIdx.x&63;
  int id=blockIdx.x*4+wv;        // 512 = b*64+k
  int b=id>>6, k=id&63;
  const u16* r=As+(size_t)k*12800+b*1600;
  float s=0.f;
  for(int i=ln;i<1600;i+=64) s+=bf2f(r[i]);
  for(int o=32;o;o>>=1) s+=__shfl_xor(s,o);
  if(ln==0) Asum[id]=s;
}

// ---------------- en epilogue (bn1d+relu) fused with mean over codes ----------------
__global__ void enmean_ep(const float* __restrict__ enraw, const float* __restrict__ Asum,
    const float* __restrict__ cw, const float* __restrict__ g, const float* __restrict__ b,
    float* __restrict__ enm){
  int bz=blockIdx.x, c=threadIdx.x;
  float s=0.f;
  for(int k=0;k<64;k++){
    float t=(enraw[((size_t)bz*64+k)*256+c]-Asum[bz*64+k]*cw[k*256+c])*g[k]+b[k];
    s+=fmaxf(t,0.f);
  }
  enm[bz*256+c]=s*(1.f/64.f);
}

// ---------------- fc + sigmoid ----------------
__global__ void fc_sig(const float* __restrict__ enm, const float* __restrict__ wfc,
    const float* __restrict__ bfc, float* __restrict__ gam){
  __shared__ float sh[256];
  int b=blockIdx.x, co=threadIdx.x;
  sh[co]=enm[b*256+co];
  __syncthreads();
  float s=bfc[co];
  for(int i=0;i<256;i++) s+=sh[i]*wfc[co*256+i];
  gam[b*256+co]=1.f/(1.f+expf(-s));
}

// ---------------- x_lvc = relu(xc*(1+gam)) -> fusebuf[:, :256] ----------------
__global__ void ew_xlvc(const u16* __restrict__ xc, const float* __restrict__ gam, u16* __restrict__ fb){
  int t=blockIdx.x*256+threadIdx.x;
  int c=(t&31)*8; int gp=t>>5; int z=gp/1600;
  u16x8 v=*(const u16x8*)(xc+(size_t)gp*256+c);
  u16x8 o;
#pragma unroll
  for(int q=0;q<8;q++){ float ga=1.f+gam[z*256+c+q]; o[q]=f2bf(fmaxf(bf2f(v[q])*ga,0.f)); }
  *(u16x8*)(fb+(size_t)gp*512+c)=o;
}

// ---------------- GN stats (sum, sumsq per batch) ----------------
__global__ void gn_stats(const u16* __restrict__ x, float* __restrict__ st){
  int z=blockIdx.y;
  const u16* pz=x+(size_t)z*409600;
  float s=0.f, ss=0.f;
  for(int i=blockIdx.x*256+threadIdx.x;i<51200;i+=gridDim.x*256){
    u16x8 v=*(const u16x8*)(pz+(size_t)i*8);
#pragma unroll
    for(int q=0;q<8;q++){ float f=bf2f(v[q]); s+=f; ss+=f*f; }
  }
  for(int o=32;o;o>>=1){ s+=__shfl_xor(s,o); ss+=__shfl_xor(ss,o); }
  __shared__ float sh[8];
  int wv=threadIdx.x>>6, ln=threadIdx.x&63;
  if(ln==0){ sh[wv]=s; sh[4+wv]=ss; }
  __syncthreads();
  if(threadIdx.x==0){
    atomicAdd(&st[z*2],  sh[0]+sh[1]+sh[2]+sh[3]);
    atomicAdd(&st[z*2+1],sh[4]+sh[5]+sh[6]+sh[7]);
  }
}

// ---------------- gn1 + dw + bn + silu ----------------
__global__ void ew_hdw(const u16* __restrict__ x1, const float* __restrict__ st,
    const float* __restrict__ g1, const float* __restrict__ b1,
    const float* __restrict__ wdw, const float* __restrict__ gdw, const float* __restrict__ bdw,
    u16* __restrict__ out){
  int t=blockIdx.x*256+threadIdx.x;
  int c=(t&31)*8; int gp=t>>5; int z=gp/1600;
  float mean=st[z*2]*(1.f/409600.f);
  float var=st[z*2+1]*(1.f/409600.f)-mean*mean;
  float rs=rsqrtf(var+1e-5f);
  u16x8 v=*(const u16x8*)(x1+(size_t)gp*256+c);
  u16x8 o;
#pragma unroll
  for(int q=0;q<8;q++){
    int cc=c+q;
    float t0=(bf2f(v[q])-mean)*rs*g1[cc]+b1[cc];
    t0=t0*wdw[cc]*gdw[cc]+bdw[cc];
    o[q]=f2bf(t0/(1.f+expf(-t0)));
  }
  *(u16x8*)(out+(size_t)gp*256+c)=o;
}

// ---------------- gn2 affine only ----------------
__global__ void ew_gn2(const u16* __restrict__ xm, const float* __restrict__ st,
    const float* __restrict__ g2, const float* __restrict__ b2, u16* __restrict__ out){
  int t=blockIdx.x*256+threadIdx.x;
  int c=(t&31)*8; int gp=t>>5; int z=gp/1600;
  float mean=st[z*2]*(1.f/409600.f);
  float var=st[z*2+1]*(1.f/409600.f)-mean*mean;
  float rs=rsqrtf(var+1e-5f);
  u16x8 v=*(const u16x8*)(xm+(size_t)gp*256+c);
  u16x8 o;
#pragma unroll
  for(int q=0;q<8;q++){ int cc=c+q; o[q]=f2bf((bf2f(v[q])-mean)*rs*g2[cc]+b2[cc]); }
  *(u16x8*)(out+(size_t)gp*256+c)=o;
}

// ---------------- launch ----------------
extern "C" void kernel_launch(void* const* d_in, const int* in_sizes, int n_in,
                              void* d_out, int out_size, void* d_ws, size_t ws_size,
                              hipStream_t stream){
  const float* X    =(const float*)d_in[0];
  const float* Wstem=(const float*)d_in[1];
  const float* Gstem=(const float*)d_in[2];
  const float* Bstem=(const float*)d_in[3];
  const float* Wcb1 =(const float*)d_in[4];
  const float* Gcb1 =(const float*)d_in[5];
  const float* Bcb1 =(const float*)d_in[6];
  const float* Wcb2 =(const float*)d_in[7];
  const float* Gcb2 =(const float*)d_in[8];
  const float* Bcb2 =(const float*)d_in[9];
  const float* Wcb3 =(const float*)d_in[10];
  const float* Gcb3 =(const float*)d_in[11];
  const float* Bcb3 =(const float*)d_in[12];
  const float* Wres =(const float*)d_in[13];
  const float* Gres =(const float*)d_in[14];
  const float* Bres =(const float*)d_in[15];
  const float* Wlvc =(const float*)d_in[16];
  const float* Glvc =(const float*)d_in[17];
  const float* Blvc =(const float*)d_in[18];
  const float* CW   =(const float*)d_in[19];
  const float* CWS  =(const float*)d_in[20];
  const float* Genc =(const float*)d_in[21];
  const float* Benc =(const float*)d_in[22];
  const float* Wfc  =(const float*)d_in[23];
  const float* Bfc  =(const float*)d_in[24];
  const float* GN1g =(const float*)d_in[25];
  const float* GN1b =(const float*)d_in[26];
  const float* Wdw  =(const float*)d_in[27];
  const float* Gdw  =(const float*)d_in[28];
  const float* Bdw  =(const float*)d_in[29];
  const float* Wpw  =(const float*)d_in[30];
  const float* Gpw  =(const float*)d_in[31];
  const float* Bpw  =(const float*)d_in[32];
  const float* GN2g =(const float*)d_in[33];
  const float* GN2b =(const float*)d_in[34];
  const float* Wfc1 =(const float*)d_in[35];
  const float* Bfc1 =(const float*)d_in[36];
  const float* Wfc2 =(const float*)d_in[37];
  const float* Bfc2 =(const float*)d_in[38];
  const float* LS1  =(const float*)d_in[39];
  const float* LS2  =(const float*)d_in[40];
  const float* Wcnv =(const float*)d_in[41];
  const float* Bcnv =(const float*)d_in[42];
  char* ws=(char*)d_ws;
  if(ws_size < TOTAL_WS) return;

  u16* xpad=(u16*)(ws+oXPAD);
  u16* t1p =(u16*)(ws+oT1P);
  float* stats=(float*)(ws+oSTAT);
  u16* wst =(u16*)(ws+oWST);
  u16* wcb2t=(u16*)(ws+oWCB2);
  u16* wsm =(u16*)(ws+oWSM);
  float* c2b=(float*)(ws+oC2);
  u16* act =(u16*)(ws+oSTEM);
  u16* x1  =(u16*)(ws+oX1);
  u16* t2  =(u16*)(ws+oT2);
  u16* rres=(u16*)(ws+oRRES);
  u16* xc  =(u16*)(ws+oXC);
  u16* zb  =(u16*)(ws+oZ);
  u16* zt  =(u16*)(ws+oZT);
  float* x2b=(float*)(ws+oX2);
  float* dotb=(float*)(ws+oDOT);
  u16* As  =(u16*)(ws+oAS);
  float* Asum=(float*)(ws+oASUM);
  float* enraw=(float*)(ws+oEN);
  float* enm=(float*)(ws+oENM);
  float* gam=(float*)(ws+oGAM);
  u16* h2a =(u16*)(ws+oH2A);
  u16* fb  =(u16*)(ws+oFUSE);
  u16* xm  =(u16*)(ws+oXPAD);   // reuse (xpad dead after stem)
  u16* xmgn=(u16*)(ws+oWST);    // reuse (stem weights dead after stem)
  u16* hdw =(u16*)(ws+oRRES);   // reuse (rres dead after cb3)
  u16* accP =(u16*)(ws+oPART);   // stem partials bf16 [7][12800][256]
  u16* accP2=(u16*)(ws+oPART2);  // cb2 partials bf16 [3][12800][64]
  u16* wcb1=wsm+0;      u16* wcb3=wsm+16384;  u16* wresb=wsm+32768; u16* wlvcb=wsm+98304;
  u16* wpwb=wsm+163840; u16* wfc1b=wsm+229376;u16* wfc2b=wsm+491520;u16* wcnvb=wsm+753664;
  u16* cwb=wsm+884736;

  hipMemsetAsync(d_ws,0,ZERO_BYTES,stream);
  { WCP p;
    p.s[0]=Wcb1;p.d[0]=wcb1;  p.s[1]=Wcb3;p.d[1]=wcb3;  p.s[2]=Wres;p.d[2]=wresb;
    p.s[3]=Wlvc;p.d[3]=wlvcb; p.s[4]=Wpw;p.d[4]=wpwb;   p.s[5]=Wfc1;p.d[5]=wfc1b;
    p.s[6]=Wfc2;p.d[6]=wfc2b; p.s[7]=Wcnv;p.d[7]=wcnvb; p.s[8]=CW;p.d[8]=cwb;
    wcast_plain<<<3520,256,0,stream>>>(p); }
  wcast_stem<<<256,256,0,stream>>>(Wstem,wst);
  wcast_cb2<<<144,256,0,stream>>>(Wcb2,wcb2t);
  c2k<<<1,64,0,stream>>>(CW,c2b);
  x_to_xpad<<<dim3(40,8),256,0,stream>>>(X,xpad);

  // stem: 7 slices (one dh row each), bf16 partials, pixel-stationary XCD pinning
  conv_lds<128,256,128,256,46,7,4,7,49,7,1><<<1456,256,0,stream>>>(xpad,wst,accP);
  ep_red<32,7><<<1600,256,0,stream>>>(accP,Gstem,Bstem,act);
  maxpool3<<<1600,256,0,stream>>>(act,x1);

  { GP p{}; p.A=wcb1;p.Asz=0;p.lda=256; p.Bp=x1;p.Bsz=1600*256;p.ldb=256; p.Kd=256;
    p.e0=Gcb1;p.e1=Bcb1; p.ob=t1p;
    gemm_nt<1,5,1><<<dim3(1,20,8),256,0,stream>>>(p); }
  // cb2: LDS-staged conv, split-K over 3 tap groups, bf16 partials
  conv_lds<64,64,128,64,42,3,2,3,9,3,0><<<dim3(1,100,3),128,0,stream>>>(t1p,wcb2t,accP2);
  ep_red<8,3><<<400,256,0,stream>>>(accP2,Gcb2,Bcb2,t2);
  { GP p{}; p.A=wresb;p.Asz=0;p.lda=256; p.Bp=x1;p.Bsz=1600*256;p.ldb=256; p.Kd=256;
    p.e0=Gres;p.e1=Bres; p.ob=rres;
    gemm_nt<2,5,2><<<dim3(2,20,8),256,0,stream>>>(p); }
  { GP p{}; p.A=wcb3;p.Asz=0;p.lda=64; p.Bp=t2;p.Bsz=1600*64;p.ldb=64; p.Kd=64;
    p.e0=Gcb3;p.e1=Bcb3; p.r0=rres; p.ob=xc;
    gemm_nt<2,5,3><<<dim3(2,20,8),256,0,stream>>>(p); }
  { GP p{}; p.A=wlvcb;p.Asz=0;p.lda=256; p.Bp=xc;p.Bsz=1600*256;p.ldb=256; p.Kd=256;
    p.e0=Glvc;p.e1=Blvc; p.ob=zb; p.ob2=zt;
    gemm_nt<2,5,4><<<dim3(2,20,8),256,0,stream>>>(p); }
  rowsq<<<3200,256,0,stream>>>(zb,x2b);
  { GP p{}; p.A=zb;p.Asz=0;p.lda=256; p.Bp=cwb;p.Bsz=0;p.ldb=256; p.Kd=256; p.of=dotb;
    gemm_nt<2,4,5><<<dim3(100,1,1),256,0,stream>>>(p); }
  softmax_k<<<200,256,0,stream>>>(dotb,x2b,c2b,CWS,As);
  asum_k<<<128,256,0,stream>>>(As,Asum);
  // enraw region was clobbered by conv partials -> zero it here (partials are dead now)
  hipMemsetAsync(enraw,0,sEN,stream);
  // aggregation: split-K (5 chunks of 320 pixels) with raw f32 atomics
  { GP p{}; p.A=As;p.Asz=1600;p.lda=12800; p.Bp=zt;p.Bsz=256*1600;p.ldb=1600; p.Kd=320;
    p.of=enraw;
    gemm_nt<1,4,11><<<dim3(1,4,40),256,0,stream>>>(p); }
  enmean_ep<<<8,256,0,stream>>>(enraw,Asum,CW,Genc,Benc,enm);
  fc_sig<<<8,256,0,stream>>>(enm,Wfc,Bfc,gam);
  ew_xlvc<<<1600,256,0,stream>>>(xc,gam,fb);

  gn_stats<<<dim3(25,8),256,0,stream>>>(x1,stats);
  ew_hdw<<<1600,256,0,stream>>>(x1,stats,GN1g,GN1b,Wdw,Gdw,Bdw,hdw);
  { GP p{}; p.A=wpwb;p.Asz=0;p.lda=256; p.Bp=hdw;p.Bsz=1600*256;p.ldb=256; p.Kd=256;
    p.e0=Gpw;p.e1=Bpw;p.e2=LS1; p.r0=x1; p.ob=xm;
    gemm_nt<2,5,9><<<dim3(2,20,8),256,0,stream>>>(p); }
  gn_stats<<<dim3(25,8),256,0,stream>>>(xm,stats+16);
  ew_gn2<<<1600,256,0,stream>>>(xm,stats+16,GN2g,GN2b,xmgn);
  { GP p{}; p.A=wfc1b;p.Asz=0;p.lda=256; p.Bp=xmgn;p.Bsz=1600*256;p.ldb=256; p.Kd=256;
    p.e0=Bfc1; p.ob=h2a; p.ldo=1024;
    gemm_nt<2,5,7><<<dim3(8,20,8),256,0,stream>>>(p); }
  { GP p{}; p.A=wfc2b;p.Asz=0;p.lda=1024; p.Bp=h2a;p.Bsz=1600*1024;p.ldb=1024; p.Kd=1024;
    p.e0=Bfc2;p.e1=LS2; p.r0=xm; p.ob=fb+256;
    gemm_nt<2,5,8><<<dim3(2,20,8),256,0,stream>>>(p); }
  { GP p{}; p.A=wcnvb;p.Asz=0;p.lda=512; p.Bp=fb;p.Bsz=1600*512;p.ldb=512; p.Kd=512;
    p.e0=Bcnv; p.of=(float*)d_out;
    gemm_nt<2,5,10><<<dim3(2,20,8),256,0,stream>>>(p); }
}

// Round 9
// 641.628 us; speedup vs baseline: 1.2091x; 1.1058x over previous
//
#include <hip/hip_runtime.h>
#include <hip/hip_bf16.h>
#include <math.h>

typedef unsigned short u16;
typedef u16 u16x4 __attribute__((ext_vector_type(4)));
typedef u16 u16x8 __attribute__((ext_vector_type(8)));
typedef short s16x8 __attribute__((ext_vector_type(8)));
typedef float f32x4 __attribute__((ext_vector_type(4)));

#define DEVI static __device__ __forceinline__

DEVI float bf2f(u16 u){ unsigned v=((unsigned)u)<<16; float f; __builtin_memcpy(&f,&v,4); return f; }
DEVI u16 f2bf(float f){ unsigned u; __builtin_memcpy(&u,&f,4); u=(u+0x7FFFu+((u>>16)&1u))>>16; return (u16)u; }

// async global->LDS, 16B per lane. LDS dest is wave-uniform base + lane*16B;
// the lane->(row,col) placement comes from the per-lane GLOBAL address.
DEVI void gload16(const u16* g, u16* l){
  __builtin_amdgcn_global_load_lds(
      (const __attribute__((address_space(1))) void*)(unsigned long long)g,
      (__attribute__((address_space(3))) void*)(unsigned int)(unsigned long long)l,
      16, 0, 0);
}

// ---------------- workspace layout (bytes) ----------------
constexpr size_t AL(size_t x){ return (x+511)&~(size_t)511; }
constexpr size_t sACT =8ull*1600*256*2;                       // one NHWC bf16 activation (6.55 MB)
constexpr size_t oXPAD=0;                constexpr size_t sXPAD=8ull*46*46*256*2; // stem padded input; reused as xm
constexpr size_t oT1P =AL(oXPAD+sXPAD);  constexpr size_t sT1P=8ull*42*42*64*2;   // cb1 out, padded
constexpr size_t oSTAT=AL(oT1P+sT1P);    constexpr size_t sSTAT=512;              // gn1[16]+gn2[16] floats
constexpr size_t ZERO_BYTES=oSTAT+sSTAT;
constexpr size_t oWST =AL(ZERO_BYTES);   constexpr size_t sWST=6553600;           // stem w bf16 [49][256][256]; reused as xmgn
constexpr size_t oWCB2=AL(oWST+sWST);    constexpr size_t sWCB2=9*64*64*2;
constexpr size_t oWSM =AL(oWCB2+sWCB2);  constexpr size_t sWSM=901120ull*2;       // all 1x1 weights bf16
constexpr size_t oC2  =AL(oWSM+sWSM);    constexpr size_t sC2=1024;
constexpr size_t oSTEM=AL(oC2+sC2);                                                // stem conv out
constexpr size_t oX1  =AL(oSTEM+sACT);
constexpr size_t oT2  =AL(oX1+sACT);     constexpr size_t sT2=8ull*1600*64*2;
constexpr size_t oRRES=AL(oT2+sT2);                                                // cbres out; reused as hdw + conv partials
constexpr size_t oXC  =AL(oRRES+sACT);
constexpr size_t oZ   =AL(oXC+sACT);
constexpr size_t oZT  =AL(oZ+sACT);                                                // z transposed NCHW
constexpr size_t oX2  =AL(oZT+sACT);     constexpr size_t sX2=12800*4;
constexpr size_t oDOT =AL(oX2+sX2);      constexpr size_t sDOT=12800ull*64*4;
constexpr size_t oAS  =AL(oDOT+sDOT);    constexpr size_t sAS=64ull*12800*2;
constexpr size_t oASUM=AL(oAS+sAS);      constexpr size_t sASUM=512*4;
constexpr size_t oEN  =AL(oASUM+sASUM);  constexpr size_t sEN=8ull*64*256*4;      // raw agg accumulator (f32)
constexpr size_t oENM =AL(oEN+sEN);      constexpr size_t sENM=8*256*4;
constexpr size_t oGAM =AL(oENM+sENM);    constexpr size_t sGAM=8*256*4;
constexpr size_t oH2A =AL(oGAM+sGAM);    constexpr size_t sH2A=8ull*1600*1024*2;  // fc1 out
constexpr size_t oFUSE=AL(oH2A+sH2A);    constexpr size_t sFUSE=8ull*1600*512*2;
constexpr size_t TOTAL_WS=oFUSE+sFUSE;
static_assert(TOTAL_WS < ((size_t)120<<20), "ws layout ~94MB");
// conv split-K partials (bf16) overlay the dead late-stage region starting at oRRES.
constexpr size_t oPART =oRRES;             constexpr size_t sPART =7ull*12800*256*2; // 45.9 MB stem bf16
constexpr size_t oPART2=oPART+sPART;       constexpr size_t sPART2=3ull*12800*64*2;  // 4.9 MB cb2 bf16
static_assert(oPART2+sPART2<=TOTAL_WS, "partials fit");

// ---------------- weight cast kernels ----------------
struct WCP { const float* s[9]; u16* d[9]; const float* cw; float* c2; };
__global__ void wcast_plain(WCP p){
  if(blockIdx.x==3520){                       // folded-in c2k
    int k=threadIdx.x;
    if(k<64){ float s=0.f; for(int i=0;i<256;i++){ float v=p.cw[k*256+i]; s+=v*v; } p.c2[k]=s; }
    return;
  }
  int idx=blockIdx.x*256+threadIdx.x;
  int j,rel;
  if(idx<16384){j=0;rel=idx;}
  else if(idx<32768){j=1;rel=idx-16384;}
  else if(idx<98304){j=2;rel=idx-32768;}
  else if(idx<163840){j=3;rel=idx-98304;}
  else if(idx<229376){j=4;rel=idx-163840;}
  else if(idx<491520){j=5;rel=idx-229376;}
  else if(idx<753664){j=6;rel=idx-491520;}
  else if(idx<884736){j=7;rel=idx-753664;}
  else if(idx<901120){j=8;rel=idx-884736;}
  else return;
  p.d[j][rel]=f2bf(p.s[j][rel]);
}
// stem weights: [co][ci][49] f32 -> [dhw][co][ci] bf16, via LDS transpose.
__global__ void wcast_stem(const float* __restrict__ w, u16* __restrict__ o){
  __shared__ u16 sh[49*256];
  int co=blockIdx.x, ci=threadIdx.x;
  const float* src=w+(size_t)(co*256+ci)*49;
#pragma unroll 7
  for(int j=0;j<49;j++) sh[j*256+ci]=f2bf(src[j]);
  __syncthreads();
#pragma unroll 7
  for(int j=0;j<49;j++) o[((size_t)j*256+co)*256+ci]=sh[j*256+ci];
}
__global__ void wcast_cb2(const float* __restrict__ w, u16* __restrict__ o){
  int idx=blockIdx.x*256+threadIdx.x;           // 9*64*64
  if(idx>=9*4096) return;
  int ci=idx&63; int t=idx>>6; int co=t&63; int dhw=t>>6;
  o[idx]=f2bf(w[(co*64+ci)*9+dhw]);
}

// ---------------- x (NCHW f32) -> xpad (NHWC bf16, pad 3) ----------------
__global__ void x_to_xpad(const float* __restrict__ x, u16* __restrict__ xpad){
  __shared__ u16 sh[40*257];
  int h=blockIdx.x, z=blockIdx.y;
  const float* xb=x+(size_t)z*409600+h*40;
  for(int e=threadIdx.x;e<10240;e+=256){ int c=e/40, w=e-40*(e/40); sh[w*257+c]=f2bf(xb[c*1600+w]); }
  __syncthreads();
  u16* op=xpad+((size_t)(z*46+h+3)*46+3)*256;
  for(int e=threadIdx.x;e<10240;e+=256){ int w=e>>8, c=e&255; op[w*256+c]=sh[w*257+c]; }
}

// ---------------- LDS-staged implicit-GEMM conv ----------------
// Staging (r9): lane l of each gload reads global (row=l>>2, colq=(l&3)^((l>>3)&3)).
// Quads read 64B contiguous (full coalescing, = r4); the in-row column XOR makes
// the compute ds_read (fofs = (lr*4 + (kg^((lr>>1)&3)))*16B) land 2-way-per-bank
// across the wave -> free (m136). Partial stores are non-temporal (skip L2:
// the 46MB write stream was evicting streamed weights from per-XCD L2).
// XSWZ=1: pixel-stationary XCD pinning (r7-verified FETCH 312->35MB).
template<int COT,int COTOT,int PXT,int CIN,int PW,int KS,int NW,int TPS,int TTOT,int NSLICE,int XSWZ>
__global__ __launch_bounds__(NW*64) void conv_lds(
    const u16* __restrict__ Xp, const u16* __restrict__ Wt, u16* __restrict__ part){
  constexpr int WPN=PXT/64;          // waves along px
  constexpr int WGR=COT/16;          // W 16-row groups
  constexpr int AGR=PXT/16;          // A 16-row groups
  constexpr int IW=WGR/NW;           // W-group issues per wave
  constexpr int IA=AGR/NW;           // A-group issues per wave
  constexpr int CST=CIN/32;          // k-substeps per tap
  constexpr int CSH=(CST==8)?3:1;

  __shared__ __align__(16) u16 sW[2][COT*32];
  __shared__ __align__(16) u16 sA[2][PXT*32];

  const int wv=threadIdx.x>>6, ln=threadIdx.x&63, lr=ln&15, kg=ln>>4;
  const int wr=wv/WPN, wc=wv%WPN;
  const int colq=((ln&3)^((ln>>3)&3))*8;       // staging source column (u16 units)
  const int fofs=(lr*4+(kg^((lr>>1)&3)))*8;    // compute read offset (u16 units)
  int co0,px0,slice;
  if constexpr(XSWZ){
    int lin=blockIdx.x; int xcd=lin&7, rest=lin>>3;
    int combo=rest/13, pxin=rest%13;           // combo = (slice,coblk)
    int pxt=xcd*13+pxin;
    if(pxt>=100) return;                       // ragged chunk guard
    slice=combo>>1; co0=(combo&1)*COT; px0=pxt*PXT;
  } else {
    co0=blockIdx.x*COT; px0=blockIdx.y*PXT; slice=blockIdx.z;
  }
  const int tb=slice*TPS;
  const int te=(slice==NSLICE-1)?TTOT:(tb+TPS);
  const int nst=(te-tb)<<CSH;

  // coalesced per-lane global source offsets (computed once)
  int wbase[IW], abase[IA];
#pragma unroll
  for(int q=0;q<IW;q++){
    int g=wv*IW+q;
    wbase[q]=(co0+g*16+(ln>>2))*CIN+colq;
  }
#pragma unroll
  for(int q=0;q<IA;q++){
    int g=wv*IA+q;
    int p=px0+g*16+(ln>>2);
    int z=p/1600, rem=p-z*1600;
    int h=rem/40, w=rem-h*40;
    abase[q]=((z*PW+h)*PW+w)*CIN+colq;
  }

  f32x4 acc[4][4];
#pragma unroll
  for(int i=0;i<4;i++)
#pragma unroll
    for(int j=0;j<4;j++) acc[i][j]=f32x4{0.f,0.f,0.f,0.f};

  auto stage=[&](int buf,int s){
    int ti=tb+(s>>CSH);
    int c0=(s&(CST-1))<<5;
    int dh=ti/KS, dw=ti-dh*KS;
    const u16* wsrc=Wt+(size_t)ti*COTOT*CIN+c0;
    int aoff=(dh*PW+dw)*CIN+c0;
#pragma unroll
    for(int q=0;q<IW;q++) gload16(wsrc+wbase[q], &sW[buf][(wv*IW+q)*512]);
#pragma unroll
    for(int q=0;q<IA;q++) gload16(Xp+abase[q]+aoff, &sA[buf][(wv*IA+q)*512]);
  };
  auto compute=[&](int buf){
    s16x8 av[4], bv[4];
#pragma unroll
    for(int i=0;i<4;i++) av[i]=*(const s16x8*)(&sW[buf][(wr*4+i)*512+fofs]);
#pragma unroll
    for(int j=0;j<4;j++) bv[j]=*(const s16x8*)(&sA[buf][(wc*4+j)*512+fofs]);
#pragma unroll
    for(int i=0;i<4;i++)
#pragma unroll
      for(int j=0;j<4;j++)
        acc[i][j]=__builtin_amdgcn_mfma_f32_16x16x32_bf16(av[i],bv[j],acc[i][j],0,0,0);
  };

  stage(0,0);
  for(int s=0;s<nst;s++){
    __syncthreads();                       // drains prior gloads (vmcnt) + ds reads
    if(s+1<nst) stage((s+1)&1, s+1);
    compute(s&1);
  }

  u16* pb=part+(size_t)slice*12800*COTOT;
#pragma unroll
  for(int i=0;i<4;i++){
    int co=co0+wr*64+i*16+kg*4;
#pragma unroll
    for(int j=0;j<4;j++){
      int px=px0+wc*64+j*16+lr;
      u16x4 o;
#pragma unroll
      for(int q=0;q<4;q++) o[q]=f2bf(acc[i][j][q]);
      unsigned long long pk; __builtin_memcpy(&pk,&o,8);
      __builtin_nontemporal_store(pk,(unsigned long long*)(pb+(size_t)px*COTOT+co));
    }
  }
}

// ---------------- reduce bf16 partials + BN + ReLU -> bf16 NHWC ----------------
template<int MT8,int NS>   // MT8 = Ctot/8
__global__ void ep_red(const u16* __restrict__ part, const float* __restrict__ g,
    const float* __restrict__ b, u16* __restrict__ out){
  int t=blockIdx.x*256+threadIdx.x;
  int c=(t%MT8)*8; int gp=t/MT8;
  size_t base=(size_t)gp*(MT8*8)+c;
  constexpr size_t SS=(size_t)12800*MT8*8;
  float v[8];
#pragma unroll
  for(int q=0;q<8;q++) v[q]=0.f;
#pragma unroll
  for(int s=0;s<NS;s++){
    u16x8 a=*(const u16x8*)(part+s*SS+base);
#pragma unroll
    for(int q=0;q<8;q++) v[q]+=bf2f(a[q]);
  }
  u16x8 o;
#pragma unroll
  for(int q=0;q<8;q++) o[q]=f2bf(fmaxf(v[q]*g[c+q]+b[c+q],0.f));
  *(u16x8*)(out+base)=o;
}

// ---------------- maxpool 3x3 s1 p1 (NHWC bf16) ----------------
__global__ void maxpool3(const u16* __restrict__ in, u16* __restrict__ out){
  int t=blockIdx.x*256+threadIdx.x;
  int c8=(t&31)*8; int gp=t>>5;
  int n=gp%1600; int z=gp/1600; int h=n/40, w=n%40;
  float mx[8];
#pragma unroll
  for(int q=0;q<8;q++) mx[q]=-1e30f;
  for(int dh=-1;dh<=1;dh++){ int hh=h+dh; if((unsigned)hh>=40u) continue;
    for(int dw=-1;dw<=1;dw++){ int ww=w+dw; if((unsigned)ww>=40u) continue;
      u16x8 v=*(const u16x8*)(in+((size_t)z*1600+hh*40+ww)*256+c8);
#pragma unroll
      for(int q=0;q<8;q++) mx[q]=fmaxf(mx[q],bf2f(v[q]));
    }}
  u16x8 o;
#pragma unroll
  for(int q=0;q<8;q++) o[q]=f2bf(mx[q]);
  *(u16x8*)(out+((size_t)z*1600+n)*256+c8)=o;
}

// ---------------- generic NT GEMM: D[m][n] = dot(A[m,:],B[n,:]) + epilogue ----------------
struct GP {
  const u16* A; long long Asz; int lda;
  const u16* Bp; long long Bsz; int ldb;
  int Kd;
  const float *e0,*e1,*e2,*e3;
  const u16* r0;
  u16* ob; float* of; u16* ob2;
  int ldo;
};

template<int MF,int NF,int EPI>
__global__ __launch_bounds__(256) void gemm_nt(GP p){
  const int wv=threadIdx.x>>6, ln=threadIdx.x&63, lr=ln&15, kg=ln>>4;
  int z=blockIdx.z, kc=0;
  if constexpr(EPI==11){ kc=z%5; z=z/5; }        // split-K for aggregation
  const int m0=blockIdx.x*(MF*64)+wv*(MF*16);
  const int n0=blockIdx.y*(NF*16);
  const u16* A=p.A+(size_t)z*p.Asz+kc*320;
  const u16* Bb=p.Bp+(size_t)z*p.Bsz+kc*320;
  const u16* ar[MF]; const u16* br[NF];
#pragma unroll
  for(int i=0;i<MF;i++) ar[i]=A+(size_t)(m0+i*16+lr)*p.lda+kg*8;
#pragma unroll
  for(int j=0;j<NF;j++) br[j]=Bb+(size_t)(n0+j*16+lr)*p.ldb+kg*8;
  f32x4 acc[MF][NF];
#pragma unroll
  for(int i=0;i<MF;i++)
#pragma unroll
    for(int j=0;j<NF;j++) acc[i][j]=f32x4{0.f,0.f,0.f,0.f};
  for(int k=0;k<p.Kd;k+=32){
    s16x8 av[MF], bv[NF];
#pragma unroll
    for(int i=0;i<MF;i++) av[i]=*(const s16x8*)(ar[i]+k);
#pragma unroll
    for(int j=0;j<NF;j++) bv[j]=*(const s16x8*)(br[j]+k);
#pragma unroll
    for(int i=0;i<MF;i++)
#pragma unroll
      for(int j=0;j<NF;j++)
        acc[i][j]=__builtin_amdgcn_mfma_f32_16x16x32_bf16(av[i],bv[j],acc[i][j],0,0,0);
  }
#pragma unroll
  for(int i=0;i<MF;i++){
    const int mb=m0+i*16+kg*4;
#pragma unroll
    for(int j=0;j<NF;j++){
      const int n=n0+j*16+lr;
      f32x4 v=acc[i][j];
      if constexpr(EPI==1){            // cb1: bn+relu -> padded t1p [42][42][64]
        int h=n/40, w=n%40;
        u16x4 o;
#pragma unroll
        for(int q=0;q<4;q++) o[q]=f2bf(fmaxf(v[q]*p.e0[mb+q]+p.e1[mb+q],0.f));
        *(u16x4*)(p.ob+((size_t)z*1764+(h+1)*42+(w+1))*64+mb)=o;
      } else if constexpr(EPI==2){     // cbres: bn only -> NHWC 256
        u16x4 o;
#pragma unroll
        for(int q=0;q<4;q++) o[q]=f2bf(v[q]*p.e0[mb+q]+p.e1[mb+q]);
        *(u16x4*)(p.ob+((size_t)z*1600+n)*256+mb)=o;
      } else if constexpr(EPI==3){     // cb3: bn + residual + relu -> xc
        u16x4 rv=*(const u16x4*)(p.r0+((size_t)z*1600+n)*256+mb);
        u16x4 o;
#pragma unroll
        for(int q=0;q<4;q++) o[q]=f2bf(fmaxf(v[q]*p.e0[mb+q]+p.e1[mb+q]+bf2f(rv[q]),0.f));
        *(u16x4*)(p.ob+((size_t)z*1600+n)*256+mb)=o;
      } else if constexpr(EPI==4){     // lvc: bn+relu -> z NHWC + zt NCHW
        u16x4 o;
#pragma unroll
        for(int q=0;q<4;q++) o[q]=f2bf(fmaxf(v[q]*p.e0[mb+q]+p.e1[mb+q],0.f));
        *(u16x4*)(p.ob+((size_t)z*1600+n)*256+mb)=o;
#pragma unroll
        for(int q=0;q<4;q++) p.ob2[((size_t)z*256+mb+q)*1600+n]=o[q];
      } else if constexpr(EPI==5){     // dist dot: raw f32 [pix][64]
#pragma unroll
        for(int q=0;q<4;q++) p.of[(size_t)(mb+q)*64+n]=v[q];
      } else if constexpr(EPI==7){     // fc1: gelu(v+bias) -> NHWC ldo
        u16x4 o;
#pragma unroll
        for(int q=0;q<4;q++){ float t=v[q]+p.e0[mb+q]; t=0.5f*t*(1.f+erff(t*0.70710678f)); o[q]=f2bf(t); }
        *(u16x4*)(p.ob+((size_t)z*1600+n)*p.ldo+mb)=o;
      } else if constexpr(EPI==8){     // fc2: xm + ls2*(v+bias) -> fusebuf[:,256:]
        u16x4 rv=*(const u16x4*)(p.r0+((size_t)z*1600+n)*256+mb);
        u16x4 o;
#pragma unroll
        for(int q=0;q<4;q++){ float t=v[q]+p.e0[mb+q]; o[q]=f2bf(bf2f(rv[q])+p.e1[mb+q]*t); }
        *(u16x4*)(p.ob+((size_t)z*1600+n)*512+mb)=o;
      } else if constexpr(EPI==9){     // pw: x1 + ls1*silu(bn(v)) -> xm
        u16x4 rv=*(const u16x4*)(p.r0+((size_t)z*1600+n)*256+mb);
        u16x4 o;
#pragma unroll
        for(int q=0;q<4;q++){ float t=v[q]*p.e0[mb+q]+p.e1[mb+q]; float s=t/(1.f+expf(-t));
          o[q]=f2bf(bf2f(rv[q])+p.e2[mb+q]*s); }
        *(u16x4*)(p.ob+((size_t)z*1600+n)*256+mb)=o;
      } else if constexpr(EPI==10){    // fuse: v + bias -> d_out NCHW f32
#pragma unroll
        for(int q=0;q<4;q++) p.of[((size_t)z*256+mb+q)*1600+n]=v[q]+p.e0[mb+q];
      } else if constexpr(EPI==11){    // aggregation partial: atomic raw f32
#pragma unroll
        for(int q=0;q<4;q++) atomicAdd(&p.of[((size_t)z*64+mb+q)*256+n],v[q]);
      }
    }
  }
}

// ---------------- z row squared-norm ----------------
__global__ void rowsq(const u16* __restrict__ zb, float* __restrict__ x2){
  int wv=threadIdx.x>>6, ln=threadIdx.x&63;
  int gp=blockIdx.x*4+wv;
  u16x4 v=*(const u16x4*)(zb+(size_t)gp*256+ln*4);
  float s=0.f;
#pragma unroll
  for(int q=0;q<4;q++){ float f=bf2f(v[q]); s+=f*f; }
  for(int d=32;d;d>>=1) s+=__shfl_xor(s,d);
  if(ln==0) x2[gp]=s;
}

// ---------------- softmax over 64 codes; store A^T bf16 [k][12800] ----------------
__global__ void softmax_k(const float* __restrict__ dot, const float* __restrict__ x2,
    const float* __restrict__ c2, const float* __restrict__ cws, u16* __restrict__ As){
  int wv=threadIdx.x>>6, ln=threadIdx.x&63;
  int base=blockIdx.x*64+wv*16;
  float sc=cws[ln], cc=c2[ln];
  for(int it=0;it<16;it++){
    int gp=base+it;
    float d=sc*(x2[gp]-2.f*dot[(size_t)gp*64+ln]+cc);
    float m=d;
    for(int o=32;o;o>>=1) m=fmaxf(m,__shfl_xor(m,o));
    float e=expf(d-m);
    float s=e;
    for(int o=32;o;o>>=1) s+=__shfl_xor(s,o);
    As[(size_t)ln*12800+gp]=f2bf(e/s);
  }
}

// ---------------- Asum[b][k] = sum_n A ----------------
__global__ void asum_k(const u16* __restrict__ As, float* __restrict__ Asum){
  int wv=threadIdx.x>>6, ln=threadIdx.x&63;
  int id=blockIdx.x*4+wv;        // 512 = b*64+k
  int b=id>>6, k=id&63;
  const u16* r=As+(size_t)k*12800+b*1600;
  float s=0.f;
  for(int i=ln;i<1600;i+=64) s+=bf2f(r[i]);
  for(int o=32;o;o>>=1) s+=__shfl_xor(s,o);
  if(ln==0) Asum[id]=s;
}

// ---------------- en epilogue + mean + fc + sigmoid (merged) ----------------
__global__ void enc_tail(const float* __restrict__ enraw, const float* __restrict__ Asum,
    const float* __restrict__ cw, const float* __restrict__ g, const float* __restrict__ b,
    const float* __restrict__ wfc, const float* __restrict__ bfc, float* __restrict__ gam){
  __shared__ float sh[256];
  int bz=blockIdx.x, c=threadIdx.x;
  float s=0.f;
  for(int k=0;k<64;k++){
    float t=(enraw[((size_t)bz*64+k)*256+c]-Asum[bz*64+k]*cw[k*256+c])*g[k]+b[k];
    s+=fmaxf(t,0.f);
  }
  sh[c]=s*(1.f/64.f);
  __syncthreads();
  float acc=bfc[c];
  for(int i=0;i<256;i++) acc+=sh[i]*wfc[c*256+i];
  gam[bz*256+c]=1.f/(1.f+expf(-acc));
}

// ---------------- x_lvc = relu(xc*(1+gam)) -> fusebuf[:, :256] ----------------
__global__ void ew_xlvc(const u16* __restrict__ xc, const float* __restrict__ gam, u16* __restrict__ fb){
  int t=blockIdx.x*256+threadIdx.x;
  int c=(t&31)*8; int gp=t>>5; int z=gp/1600;
  u16x8 v=*(const u16x8*)(xc+(size_t)gp*256+c);
  u16x8 o;
#pragma unroll
  for(int q=0;q<8;q++){ float ga=1.f+gam[z*256+c+q]; o[q]=f2bf(fmaxf(bf2f(v[q])*ga,0.f)); }
  *(u16x8*)(fb+(size_t)gp*512+c)=o;
}

// ---------------- GN stats (sum, sumsq per batch) ----------------
__global__ void gn_stats(const u16* __restrict__ x, float* __restrict__ st){
  int z=blockIdx.y;
  const u16* pz=x+(size_t)z*409600;
  float s=0.f, ss=0.f;
  for(int i=blockIdx.x*256+threadIdx.x;i<51200;i+=gridDim.x*256){
    u16x8 v=*(const u16x8*)(pz+(size_t)i*8);
#pragma unroll
    for(int q=0;q<8;q++){ float f=bf2f(v[q]); s+=f; ss+=f*f; }
  }
  for(int o=32;o;o>>=1){ s+=__shfl_xor(s,o); ss+=__shfl_xor(ss,o); }
  __shared__ float sh[8];
  int wv=threadIdx.x>>6, ln=threadIdx.x&63;
  if(ln==0){ sh[wv]=s; sh[4+wv]=ss; }
  __syncthreads();
  if(threadIdx.x==0){
    atomicAdd(&st[z*2],  sh[0]+sh[1]+sh[2]+sh[3]);
    atomicAdd(&st[z*2+1],sh[4]+sh[5]+sh[6]+sh[7]);
  }
}

// ---------------- gn1 + dw + bn + silu ----------------
__global__ void ew_hdw(const u16* __restrict__ x1, const float* __restrict__ st,
    const float* __restrict__ g1, const float* __restrict__ b1,
    const float* __restrict__ wdw, const float* __restrict__ gdw, const float* __restrict__ bdw,
    u16* __restrict__ out){
  int t=blockIdx.x*256+threadIdx.x;
  int c=(t&31)*8; int gp=t>>5; int z=gp/1600;
  float mean=st[z*2]*(1.f/409600.f);
  float var=st[z*2+1]*(1.f/409600.f)-mean*mean;
  float rs=rsqrtf(var+1e-5f);
  u16x8 v=*(const u16x8*)(x1+(size_t)gp*256+c);
  u16x8 o;
#pragma unroll
  for(int q=0;q<8;q++){
    int cc=c+q;
    float t0=(bf2f(v[q])-mean)*rs*g1[cc]+b1[cc];
    t0=t0*wdw[cc]*gdw[cc]+bdw[cc];
    o[q]=f2bf(t0/(1.f+expf(-t0)));
  }
  *(u16x8*)(out+(size_t)gp*256+c)=o;
}

// ---------------- gn2 affine only ----------------
__global__ void ew_gn2(const u16* __restrict__ xm, const float* __restrict__ st,
    const float* __restrict__ g2, const float* __restrict__ b2, u16* __restrict__ out){
  int t=blockIdx.x*256+threadIdx.x;
  int c=(t&31)*8; int gp=t>>5; int z=gp/1600;
  float mean=st[z*2]*(1.f/409600.f);
  float var=st[z*2+1]*(1.f/409600.f)-mean*mean;
  float rs=rsqrtf(var+1e-5f);
  u16x8 v=*(const u16x8*)(xm+(size_t)gp*256+c);
  u16x8 o;
#pragma unroll
  for(int q=0;q<8;q++){ int cc=c+q; o[q]=f2bf((bf2f(v[q])-mean)*rs*g2[cc]+b2[cc]); }
  *(u16x8*)(out+(size_t)gp*256+c)=o;
}

// ---------------- launch ----------------
extern "C" void kernel_launch(void* const* d_in, const int* in_sizes, int n_in,
                              void* d_out, int out_size, void* d_ws, size_t ws_size,
                              hipStream_t stream){
  const float* X    =(const float*)d_in[0];
  const float* Wstem=(const float*)d_in[1];
  const float* Gstem=(const float*)d_in[2];
  const float* Bstem=(const float*)d_in[3];
  const float* Wcb1 =(const float*)d_in[4];
  const float* Gcb1 =(const float*)d_in[5];
  const float* Bcb1 =(const float*)d_in[6];
  const float* Wcb2 =(const float*)d_in[7];
  const float* Gcb2 =(const float*)d_in[8];
  const float* Bcb2 =(const float*)d_in[9];
  const float* Wcb3 =(const float*)d_in[10];
  const float* Gcb3 =(const float*)d_in[11];
  const float* Bcb3 =(const float*)d_in[12];
  const float* Wres =(const float*)d_in[13];
  const float* Gres =(const float*)d_in[14];
  const float* Bres =(const float*)d_in[15];
  const float* Wlvc =(const float*)d_in[16];
  const float* Glvc =(const float*)d_in[17];
  const float* Blvc =(const float*)d_in[18];
  const float* CW   =(const float*)d_in[19];
  const float* CWS  =(const float*)d_in[20];
  const float* Genc =(const float*)d_in[21];
  const float* Benc =(const float*)d_in[22];
  const float* Wfc  =(const float*)d_in[23];
  const float* Bfc  =(const float*)d_in[24];
  const float* GN1g =(const float*)d_in[25];
  const float* GN1b =(const float*)d_in[26];
  const float* Wdw  =(const float*)d_in[27];
  const float* Gdw  =(const float*)d_in[28];
  const float* Bdw  =(const float*)d_in[29];
  const float* Wpw  =(const float*)d_in[30];
  const float* Gpw  =(const float*)d_in[31];
  const float* Bpw  =(const float*)d_in[32];
  const float* GN2g =(const float*)d_in[33];
  const float* GN2b =(const float*)d_in[34];
  const float* Wfc1 =(const float*)d_in[35];
  const float* Bfc1 =(const float*)d_in[36];
  const float* Wfc2 =(const float*)d_in[37];
  const float* Bfc2 =(const float*)d_in[38];
  const float* LS1  =(const float*)d_in[39];
  const float* LS2  =(const float*)d_in[40];
  const float* Wcnv =(const float*)d_in[41];
  const float* Bcnv =(const float*)d_in[42];
  char* ws=(char*)d_ws;
  if(ws_size < TOTAL_WS) return;

  u16* xpad=(u16*)(ws+oXPAD);
  u16* t1p =(u16*)(ws+oT1P);
  float* stats=(float*)(ws+oSTAT);
  u16* wst =(u16*)(ws+oWST);
  u16* wcb2t=(u16*)(ws+oWCB2);
  u16* wsm =(u16*)(ws+oWSM);
  float* c2b=(float*)(ws+oC2);
  u16* act =(u16*)(ws+oSTEM);
  u16* x1  =(u16*)(ws+oX1);
  u16* t2  =(u16*)(ws+oT2);
  u16* rres=(u16*)(ws+oRRES);
  u16* xc  =(u16*)(ws+oXC);
  u16* zb  =(u16*)(ws+oZ);
  u16* zt  =(u16*)(ws+oZT);
  float* x2b=(float*)(ws+oX2);
  float* dotb=(float*)(ws+oDOT);
  u16* As  =(u16*)(ws+oAS);
  float* Asum=(float*)(ws+oASUM);
  float* enraw=(float*)(ws+oEN);
  float* gam=(float*)(ws+oGAM);
  u16* h2a =(u16*)(ws+oH2A);
  u16* fb  =(u16*)(ws+oFUSE);
  u16* xm  =(u16*)(ws+oXPAD);   // reuse (xpad dead after stem)
  u16* xmgn=(u16*)(ws+oWST);    // reuse (stem weights dead after stem)
  u16* hdw =(u16*)(ws+oRRES);   // reuse (rres dead after cb3)
  u16* accP =(u16*)(ws+oPART);   // stem partials bf16 [7][12800][256]
  u16* accP2=(u16*)(ws+oPART2);  // cb2 partials bf16 [3][12800][64]
  u16* wcb1=wsm+0;      u16* wcb3=wsm+16384;  u16* wresb=wsm+32768; u16* wlvcb=wsm+98304;
  u16* wpwb=wsm+163840; u16* wfc1b=wsm+229376;u16* wfc2b=wsm+491520;u16* wcnvb=wsm+753664;
  u16* cwb=wsm+884736;

  hipMemsetAsync(d_ws,0,ZERO_BYTES,stream);
  { WCP p;
    p.s[0]=Wcb1;p.d[0]=wcb1;  p.s[1]=Wcb3;p.d[1]=wcb3;  p.s[2]=Wres;p.d[2]=wresb;
    p.s[3]=Wlvc;p.d[3]=wlvcb; p.s[4]=Wpw;p.d[4]=wpwb;   p.s[5]=Wfc1;p.d[5]=wfc1b;
    p.s[6]=Wfc2;p.d[6]=wfc2b; p.s[7]=Wcnv;p.d[7]=wcnvb; p.s[8]=CW;p.d[8]=cwb;
    p.cw=CW; p.c2=c2b;
    wcast_plain<<<3521,256,0,stream>>>(p); }
  wcast_stem<<<256,256,0,stream>>>(Wstem,wst);
  wcast_cb2<<<144,256,0,stream>>>(Wcb2,wcb2t);
  x_to_xpad<<<dim3(40,8),256,0,stream>>>(X,xpad);

  // stem: 7 slices, coalesced+swizzled staging, nt partial stores, px-pinned XCDs
  conv_lds<128,256,128,256,46,7,4,7,49,7,1><<<1456,256,0,stream>>>(xpad,wst,accP);
  ep_red<32,7><<<1600,256,0,stream>>>(accP,Gstem,Bstem,act);
  maxpool3<<<1600,256,0,stream>>>(act,x1);

  { GP p{}; p.A=wcb1;p.Asz=0;p.lda=256; p.Bp=x1;p.Bsz=1600*256;p.ldb=256; p.Kd=256;
    p.e0=Gcb1;p.e1=Bcb1; p.ob=t1p;
    gemm_nt<1,5,1><<<dim3(1,20,8),256,0,stream>>>(p); }
  // cb2: LDS-staged conv, split-K over 3 tap groups, bf16 partials
  conv_lds<64,64,128,64,42,3,2,3,9,3,0><<<dim3(1,100,3),128,0,stream>>>(t1p,wcb2t,accP2);
  ep_red<8,3><<<400,256,0,stream>>>(accP2,Gcb2,Bcb2,t2);
  { GP p{}; p.A=wresb;p.Asz=0;p.lda=256; p.Bp=x1;p.Bsz=1600*256;p.ldb=256; p.Kd=256;
    p.e0=Gres;p.e1=Bres; p.ob=rres;
    gemm_nt<2,5,2><<<dim3(2,20,8),256,0,stream>>>(p); }
  { GP p{}; p.A=wcb3;p.Asz=0;p.lda=64; p.Bp=t2;p.Bsz=1600*64;p.ldb=64; p.Kd=64;
    p.e0=Gcb3;p.e1=Bcb3; p.r0=rres; p.ob=xc;
    gemm_nt<2,5,3><<<dim3(2,20,8),256,0,stream>>>(p); }
  { GP p{}; p.A=wlvcb;p.Asz=0;p.lda=256; p.Bp=xc;p.Bsz=1600*256;p.ldb=256; p.Kd=256;
    p.e0=Glvc;p.e1=Blvc; p.ob=zb; p.ob2=zt;
    gemm_nt<2,5,4><<<dim3(2,20,8),256,0,stream>>>(p); }
  rowsq<<<3200,256,0,stream>>>(zb,x2b);
  { GP p{}; p.A=zb;p.Asz=0;p.lda=256; p.Bp=cwb;p.Bsz=0;p.ldb=256; p.Kd=256; p.of=dotb;
    gemm_nt<2,4,5><<<dim3(100,1,1),256,0,stream>>>(p); }
  softmax_k<<<200,256,0,stream>>>(dotb,x2b,c2b,CWS,As);
  asum_k<<<128,256,0,stream>>>(As,Asum);
  // enraw region was clobbered by conv partials -> zero it here (partials are dead now)
  hipMemsetAsync(enraw,0,sEN,stream);
  // aggregation: split-K (5 chunks of 320 pixels) with raw f32 atomics
  { GP p{}; p.A=As;p.Asz=1600;p.lda=12800; p.Bp=zt;p.Bsz=256*1600;p.ldb=1600; p.Kd=320;
    p.of=enraw;
    gemm_nt<1,4,11><<<dim3(1,4,40),256,0,stream>>>(p); }
  enc_tail<<<8,256,0,stream>>>(enraw,Asum,CW,Genc,Benc,Wfc,Bfc,gam);
  ew_xlvc<<<1600,256,0,stream>>>(xc,gam,fb);

  gn_stats<<<dim3(25,8),256,0,stream>>>(x1,stats);
  ew_hdw<<<1600,256,0,stream>>>(x1,stats,GN1g,GN1b,Wdw,Gdw,Bdw,hdw);
  { GP p{}; p.A=wpwb;p.Asz=0;p.lda=256; p.Bp=hdw;p.Bsz=1600*256;p.ldb=256; p.Kd=256;
    p.e0=Gpw;p.e1=Bpw;p.e2=LS1; p.r0=x1; p.ob=xm;
    gemm_nt<2,5,9><<<dim3(2,20,8),256,0,stream>>>(p); }
  gn_stats<<<dim3(25,8),256,0,stream>>>(xm,stats+16);
  ew_gn2<<<1600,256,0,stream>>>(xm,stats+16,GN2g,GN2b,xmgn);
  { GP p{}; p.A=wfc1b;p.Asz=0;p.lda=256; p.Bp=xmgn;p.Bsz=1600*256;p.ldb=256; p.Kd=256;
    p.e0=Bfc1; p.ob=h2a; p.ldo=1024;
    gemm_nt<2,5,7><<<dim3(8,20,8),256,0,stream>>>(p); }
  { GP p{}; p.A=wfc2b;p.Asz=0;p.lda=1024; p.Bp=h2a;p.Bsz=1600*1024;p.ldb=1024; p.Kd=1024;
    p.e0=Bfc2;p.e1=LS2; p.r0=xm; p.ob=fb+256;
    gemm_nt<2,5,8><<<dim3(2,20,8),256,0,stream>>>(p); }
  { GP p{}; p.A=wcnvb;p.Asz=0;p.lda=512; p.Bp=fb;p.Bsz=1600*512;p.ldb=512; p.Kd=512;
    p.e0=Bcnv; p.of=(float*)d_out;
    gemm_nt<2,5,10><<<dim3(2,20,8),256,0,stream>>>(p); }
}